// Round 7
// baseline (365.190 us; speedup 1.0000x reference)
//
#include <hip/hip_runtime.h>
#include <hip/hip_bf16.h>
#include <cstdint>
#include <cstddef>

#define D_MODEL 2048
#define NH 32
#define NKV 8
#define HD 64
#define BB 2
#define LL 2048
#define EPS 1e-6f
#define MM (BB * LL)   // 4096
#define QS 3072        // fused qkv row stride
#define KO 2048        // k column offset in qkv
#define VO 2560        // v column offset in qkv
// softmax fold: q pre-scaled by 0.125*log2(e); p = 2^(S - 8*log2(e))
#define QSCALE 0.18033688f
#define SM_BIAS 11.5415603f

typedef __hip_bfloat16 bf16;
typedef short bf16x8 __attribute__((ext_vector_type(8)));
typedef short s16x4 __attribute__((ext_vector_type(4)));
typedef float f32x4 __attribute__((ext_vector_type(4)));

// ---- dtype helpers ---------------------------------------------------------
__device__ inline float4 ld_bf4u(const unsigned short* p) {
  const ushort4 u = *(const ushort4*)p;
  float4 r;
  r.x = __uint_as_float(((unsigned)u.x) << 16);
  r.y = __uint_as_float(((unsigned)u.y) << 16);
  r.z = __uint_as_float(((unsigned)u.z) << 16);
  r.w = __uint_as_float(((unsigned)u.w) << 16);
  return r;
}
__device__ inline float4 ld4_rt(const void* p, size_t i, bool f32) {
  if (f32) return *(const float4*)((const float*)p + i);
  return ld_bf4u((const unsigned short*)p + i);
}
__device__ inline float ld1_rt(const void* p, size_t i, bool f32) {
  if (f32) return ((const float*)p)[i];
  unsigned short u = ((const unsigned short*)p)[i];
  return __uint_as_float(((unsigned)u) << 16);
}
__device__ inline unsigned short f2bf(float f) {
  bf16 h = __float2bfloat16(f);  // RNE
  return *reinterpret_cast<unsigned short*>(&h);
}
__device__ inline float bfu2f(unsigned short u) {
  return __uint_as_float(((unsigned)u) << 16);
}
__device__ inline void store1(float* p, float v) { *p = v; }
__device__ inline void store1(unsigned short* p, float v) { *p = f2bf(v); }

// async global->LDS, 16 B per lane; LDS dest must be wave-uniform base + lane*16
__device__ inline void glds16(const unsigned short* g, unsigned short* l) {
  __builtin_amdgcn_global_load_lds(
      (const __attribute__((address_space(1))) unsigned int*)g,
      (__attribute__((address_space(3))) unsigned int*)l, 16, 0, 0);
}

// ---- per-input dtype detector (sampled, vectorized) ------------------------
__global__ __launch_bounds__(256) void detect_all(
    const unsigned short* p0, const unsigned short* p1, const unsigned short* p2,
    const unsigned short* p3, const unsigned short* p4, const unsigned short* p5,
    const unsigned short* p6, int* __restrict__ flags) {
  const unsigned short* ptrs[7] = {p0, p1, p2, p3, p4, p5, p6};
  const int b = blockIdx.x;
  const uint4* p = (const uint4*)ptrs[b];  // 8 words per uint4
  __shared__ int found;
  if (threadIdx.x == 0) found = 0;
  __syncthreads();
  int loc = 0;
#pragma unroll
  for (int it = 0; it < 16; ++it) {
    uint4 v = p[it * 256 + threadIdx.x];
    unsigned wds[4] = {v.x, v.y, v.z, v.w};
#pragma unroll
    for (int q = 0; q < 4; ++q) {
      unsigned lo = wds[q] & 0xFFFFu, hi = wds[q] >> 16;
      if (((lo >> 7) & 0xFFu) == 0xFFu || ((hi >> 7) & 0xFFu) == 0xFFu) loc = 1;
    }
  }
  if (loc) atomicOr(&found, 1);
  __syncthreads();
  if (threadIdx.x == 0) flags[b] = found;
}

// ---- prep: elementwise convert to bf16 -------------------------------------
__global__ __launch_bounds__(256) void cvt_bf16(const void* __restrict__ src,
                                                unsigned short* __restrict__ dst,
                                                int n4, const int* __restrict__ flags, int idx) {
  const bool f32 = flags[idx] != 0;
  int i = blockIdx.x * 256 + threadIdx.x;
  if (i < n4) {
    float4 v = ld4_rt(src, (size_t)i * 4, f32);
    ushort4 o;
    o.x = f2bf(v.x); o.y = f2bf(v.y); o.z = f2bf(v.z); o.w = f2bf(v.w);
    *(ushort4*)&dst[(size_t)i * 4] = o;
  }
}

// ---- prep: all 4 weight transposes in one launch ---------------------------
__global__ __launch_bounds__(256) void transpose_all(
    const void* __restrict__ Wq, const void* __restrict__ Wk,
    const void* __restrict__ Wv, const void* __restrict__ Wo,
    unsigned short* __restrict__ WqkvT, unsigned short* __restrict__ WoT,
    const int* __restrict__ flags) {
  const int z = blockIdx.z;
  const void* srcs[4] = {Wq, Wk, Wv, Wo};
  unsigned short* dsts[4] = {WqkvT, WqkvT + (size_t)KO * 2048, WqkvT + (size_t)VO * 2048, WoT};
  const int Ns[4] = {2048, 512, 512, 2048};
  const int N = Ns[z];
  if (blockIdx.x * 64 >= N) return;
  const void* src = srcs[z];
  unsigned short* dst = dsts[z];
  const bool f32 = flags[3 + z] != 0;
  const int K = 2048;
  __shared__ unsigned short tile[64][65];
  const int t = threadIdx.x;
  const int n0 = blockIdx.x * 64, k0 = blockIdx.y * 64;
  const int cr = t >> 4, cc = (t & 15) * 4;
#pragma unroll
  for (int rr = 0; rr < 4; ++rr) {
    int row = rr * 16 + cr;
    float4 v = ld4_rt(src, (size_t)(k0 + row) * N + n0 + cc, f32);
    tile[row][cc + 0] = f2bf(v.x);
    tile[row][cc + 1] = f2bf(v.y);
    tile[row][cc + 2] = f2bf(v.z);
    tile[row][cc + 3] = f2bf(v.w);
  }
  __syncthreads();
#pragma unroll
  for (int rr = 0; rr < 4; ++rr) {
    int nrow = rr * 16 + cr;
    ushort4 o;
    o.x = tile[cc + 0][nrow];
    o.y = tile[cc + 1][nrow];
    o.z = tile[cc + 2][nrow];
    o.w = tile[cc + 3][nrow];
    *(ushort4*)&dst[(size_t)(n0 + nrow) * K + k0 + cc] = o;
  }
}

// ---------------------------------------------------------------------------
// MFMA GEMM, 128x128 tile, 3-buffer counted-vmcnt pipeline + REGISTER FRAG
// DOUBLE-BUFFER: at step t, tile t+1's LDS data is already guaranteed by the
// vmcnt(4), so its fragments are prefetched into registers DURING step t --
// the MFMAs at step t+1 start with no lgkm wait on their operands.
// K-loop 2x-unrolled (T even) so frag reg sets f0/f1 are statically named
// (rule #20: no runtime-indexed vector arrays); LDS buffer rotation is a
// scalar 3-way rotate (cur/pf/st short-offsets).
// LDS chunk swizzle (both-sides, rule #21): conflict-free (R5: conflicts=0).
// FUSE=1: QKV epilogue: RoPE+RMSNorm on q/k heads (q pre-scaled by QSCALE);
// V heads written TRANSPOSED directly to vt[b][kvh][d][L].
// ---------------------------------------------------------------------------
template <typename CT, int FUSE>
__global__ __launch_bounds__(256) void gemm_mfma(const unsigned short* __restrict__ A,
                                                 const unsigned short* __restrict__ Bt,
                                                 CT* __restrict__ C,
                                                 int M, int N, int K, int lda,
                                                 const void* __restrict__ cosp,
                                                 const void* __restrict__ sinp,
                                                 const int* __restrict__ flags,
                                                 unsigned short* __restrict__ vt) {
  __shared__ __align__(16) unsigned short As[3][128 * 32];  // [128][32], chunk-swizzled
  __shared__ __align__(16) unsigned short Bs[3][128 * 32];
  const int t = threadIdx.x;
  const int lane = t & 63, w = t >> 6;
  const int wm = (w >> 1) * 64, wn = (w & 1) * 64;
  const int g = lane >> 4, m16 = lane & 15;
  // XCD swizzle: blocks resident on one XCD get a contiguous chunk of work ids
  const int nwg = gridDim.x * gridDim.y;
  const int orig = blockIdx.y * gridDim.x + blockIdx.x;
  const int swz = (orig & 7) * (nwg >> 3) + (orig >> 3);
  const int m0 = (swz / gridDim.x) * 128, n0 = (swz % gridDim.x) * 128;
  // staged source chunk for this thread (inverse of the read-side XOR)
  const int csw = (t & 3) ^ ((t >> 3) & 3);
  const unsigned short* gA = &A[(size_t)(m0 + (t >> 2)) * lda + csw * 8];
  const unsigned short* gB = &Bt[(size_t)(n0 + (t >> 2)) * K + csw * 8];
  const int l8 = t * 8;
  // read-side swizzled chunk (shorts offset within a 32-short row)
  const int cs8 = (g ^ ((m16 >> 1) & 3)) * 8;
  f32x4 acc[4][4] = {};
  const int T = K >> 5;  // K/32 k-steps (even for all our K)

#define STAGE(k0_, off_)                                                    \
  do {                                                                      \
    glds16(gA + (k0_), &As[0][0] + (off_) + l8);                            \
    glds16(gA + (size_t)64 * lda + (k0_), &As[0][0] + (off_) + 2048 + l8);  \
    glds16(gB + (k0_), &Bs[0][0] + (off_) + l8);                            \
    glds16(gB + (size_t)64 * K + (k0_), &Bs[0][0] + (off_) + 2048 + l8);    \
  } while (0)
#define LDF(fa_, fb_, off_)                                                               \
  do {                                                                                    \
    _Pragma("unroll") for (int i_ = 0; i_ < 4; ++i_)                                      \
      fa_[i_] = *(const bf16x8*)(&As[0][0] + (off_) + (wm + i_ * 16 + m16) * 32 + cs8);   \
    _Pragma("unroll") for (int j_ = 0; j_ < 4; ++j_)                                      \
      fb_[j_] = *(const bf16x8*)(&Bs[0][0] + (off_) + (wn + j_ * 16 + m16) * 32 + cs8);   \
  } while (0)
#define MF(fa_, fb_)                                                   \
  do {                                                                 \
    _Pragma("unroll") for (int i_ = 0; i_ < 4; ++i_)                   \
      _Pragma("unroll") for (int j_ = 0; j_ < 4; ++j_)                 \
        acc[i_][j_] = __builtin_amdgcn_mfma_f32_16x16x32_bf16(         \
            fa_[i_], fb_[j_], acc[i_][j_], 0, 0, 0);                   \
  } while (0)

  // prologue: tiles 0 and 1 in flight; wait tile 0; prefetch its frags
  STAGE(0, 0);
  STAGE(32, 4096);
  asm volatile("s_waitcnt vmcnt(4)" ::: "memory");
  __builtin_amdgcn_s_barrier();
  bf16x8 a0[4], b0[4], a1[4], b1[4];
  LDF(a0, b0, 0);
  int cur = 0, pf = 4096, st = 8192;  // LDS short-offsets of buf(t), buf(t+1), buf(t+2)
  for (int tt = 0; tt < T; tt += 2) {
    // ---- even step tt: compute f0 (tile tt), prefetch f1 (tile tt+1) ----
    if (tt + 2 < T) STAGE((tt + 2) << 5, st);
    if (tt + 3 < T) asm volatile("s_waitcnt vmcnt(4)" ::: "memory");
    else            asm volatile("s_waitcnt vmcnt(0)" ::: "memory");
    LDF(a1, b1, pf);  // tile tt+1 (always valid: vmcnt above guarantees it)
    MF(a0, b0);
    __builtin_amdgcn_s_barrier();
    { int tmp = cur; cur = pf; pf = st; st = tmp; }
    // ---- odd step tt+1: compute f1 (tile tt+1), prefetch f0 (tile tt+2) ----
    if (tt + 3 < T) STAGE((tt + 3) << 5, st);
    if (tt + 4 < T) asm volatile("s_waitcnt vmcnt(4)" ::: "memory");
    else            asm volatile("s_waitcnt vmcnt(0)" ::: "memory");
    if (tt + 2 < T) LDF(a0, b0, pf);  // tile tt+2
    MF(a1, b1);
    if (tt + 2 < T) __builtin_amdgcn_s_barrier();
    { int tmp = cur; cur = pf; pf = st; st = tmp; }
  }
#undef STAGE
#undef LDF
#undef MF

  if constexpr (FUSE) {
    const int colbase = n0 + wn;          // 64-aligned -> exactly one head/wave
    if (colbase < VO) {                   // q or k head: RoPE + RMSNorm
      const bool cf = flags[1] != 0, sf = flags[2] != 0;
      const float post = (colbase < KO) ? QSCALE : 1.0f;  // q: fold softmax scale
#pragma unroll
      for (int i = 0; i < 4; ++i)
#pragma unroll
        for (int r = 0; r < 4; ++r) {
          const int row = m0 + wm + i * 16 + g * 4 + r;
          const int l = row & (LL - 1);
          const float c0 = ld1_rt(cosp, l * 32 + m16, cf);
          const float c1 = ld1_rt(cosp, l * 32 + 16 + m16, cf);
          const float s0 = ld1_rt(sinp, l * 32 + m16, sf);
          const float s1 = ld1_rt(sinp, l * 32 + 16 + m16, sf);
          const float x0 = acc[i][0][r], x1 = acc[i][1][r];
          const float x2 = acc[i][2][r], x3 = acc[i][3][r];
          const float r0 = x0 * c0 - x2 * s0;
          const float r1 = x1 * c1 - x3 * s1;
          const float r2 = x2 * c0 + x0 * s0;
          const float r3 = x3 * c1 + x1 * s1;
          float ss = r0 * r0 + r1 * r1 + r2 * r2 + r3 * r3;
#pragma unroll
          for (int off = 1; off < 16; off <<= 1) ss += __shfl_xor(ss, off);
          const float sc = rsqrtf(ss * (1.0f / HD) + EPS) * post;
          CT* cr = &C[(size_t)row * N + colbase + m16];
          store1(cr + 0, r0 * sc);
          store1(cr + 16, r1 * sc);
          store1(cr + 32, r2 * sc);
          store1(cr + 48, r3 * sc);
        }
    } else {
      // V head: write transposed into vt[b][kvh][d=64][L]
      const int bb = (m0 + wm) >> 11;            // row block's batch
      const int lb = (m0 + wm) & (LL - 1);       // row block's l base
      const int kvh = (colbase - VO) >> 6;
      unsigned short* vb = vt + (size_t)(bb * NKV + kvh) * 64 * LL;
#pragma unroll
      for (int j = 0; j < 4; ++j)
#pragma unroll
        for (int i = 0; i < 4; ++i) {
          ushort4 pw;
          pw.x = f2bf(acc[i][j][0]); pw.y = f2bf(acc[i][j][1]);
          pw.z = f2bf(acc[i][j][2]); pw.w = f2bf(acc[i][j][3]);
          *(ushort4*)&vb[(size_t)(j * 16 + m16) * LL + lb + i * 16 + g * 4] = pw;
        }
    }
    return;
  }
#pragma unroll
  for (int i = 0; i < 4; ++i)
#pragma unroll
    for (int j = 0; j < 4; ++j)
#pragma unroll
      for (int r = 0; r < 4; ++r) {
        int row = m0 + wm + i * 16 + g * 4 + r;
        int col = n0 + wn + j * 16 + m16;
        store1(&C[(size_t)row * N + col], acc[i][j][r]);
      }
}

// ---------------------------------------------------------------------------
// MFMA causal GQA flash attention with STATIC-MAX softmax (R5 + T5 setprio
// around the MFMA clusters: attn blocks are independent 4-wave units, the
// catalog's +4-7% attn case, m191).
// ---------------------------------------------------------------------------
__global__ __launch_bounds__(256) void attn_mfma(unsigned short* __restrict__ qkv,
                                                 const unsigned short* __restrict__ vt) {
  __shared__ __align__(16) unsigned short Ks[2][64 * 64];  // [key][d], chunk-swizzled
  __shared__ __align__(16) unsigned short Vs[2][64 * 64];  // [d][key], chunk-swizzled
  __shared__ __align__(16) unsigned short Pt[4][64 * 16];  // per-wave P^T [key][qrow]
  const int t = threadIdx.x, lane = t & 63, w = t >> 6;
  const int g = lane >> 4, m16 = lane & 15;
  const int h = blockIdx.x, b = blockIdx.y;
  const int qt = (LL / 64 - 1) - blockIdx.z;  // longest blocks dispatch first
  const int kvh = h >> 2;
  const int q0 = qt * 64, qr0 = q0 + w * 16;

  bf16x8 qf0, qf1;
  {
    const unsigned short* qrow = &qkv[(size_t)(b * LL + qr0 + m16) * QS + h * 64 + g * 8];
    qf0 = *(const bf16x8*)&qrow[0];
    qf1 = *(const bf16x8*)&qrow[32];
  }
  f32x4 Oacc[4] = {};
  float lrow[4] = {0.f, 0.f, 0.f, 0.f};

  const int lr = lane >> 3;            // row within the 8-row group
  const int lc = (lane & 7) ^ lr;      // swizzled source 16B chunk
  const unsigned short* gK = &qkv[(size_t)(b * LL) * QS + KO + kvh * 64 + lc * 8];
  const unsigned short* gV = &vt[((size_t)(b * NKV + kvh) * 64 + w * 16 + lr) * LL + lc * 8];
  const int dbase = w * 1024 + lane * 8;  // LDS dest (shorts): wave-linear
  const int nIter = q0 / 64 + 1;

  // prologue: stage tile 0 into buffer 0
#pragma unroll
  for (int c = 0; c < 2; ++c) {
    glds16(gK + (size_t)(w * 16 + c * 8 + lr) * QS, &Ks[0][dbase + c * 512]);
    glds16(gV + (size_t)c * 8 * LL, &Vs[0][dbase + c * 512]);
  }
  __syncthreads();  // vmcnt(0) drain included

  const int sw8 = (m16 & 7) * 8;  // read-side chunk swizzle (shorts)
  for (int it = 0; it < nIter; ++it) {
    const int j0 = it * 64;
    const int cur = it & 1;
    if (it + 1 < nIter) {  // prefetch next tile into the other buffer
      const int nj = j0 + 64;
#pragma unroll
      for (int c = 0; c < 2; ++c) {
        glds16(gK + (size_t)(nj + w * 16 + c * 8 + lr) * QS, &Ks[cur ^ 1][dbase + c * 512]);
        glds16(gV + (size_t)c * 8 * LL + nj, &Vs[cur ^ 1][dbase + c * 512]);
      }
    }
    const unsigned short* KsB = Ks[cur];
    const unsigned short* VsB = Vs[cur];

    // S = Q K^T
    f32x4 S[4];
    __builtin_amdgcn_s_setprio(1);
#pragma unroll
    for (int jt = 0; jt < 4; ++jt) {
      const int rb = (jt * 16 + m16) * 64;
      bf16x8 kf0 = *(const bf16x8*)&KsB[rb + ((g * 8) ^ sw8)];
      bf16x8 kf1 = *(const bf16x8*)&KsB[rb + (((g + 4) * 8) ^ sw8)];
      f32x4 z = {0.f, 0.f, 0.f, 0.f};
      z = __builtin_amdgcn_mfma_f32_16x16x32_bf16(qf0, kf0, z, 0, 0, 0);
      S[jt] = __builtin_amdgcn_mfma_f32_16x16x32_bf16(qf1, kf1, z, 0, 0, 0);
    }
    __builtin_amdgcn_s_setprio(0);
    // static-max softmax: p = 2^(S - SM_BIAS); mask only on the diagonal tile
    if (j0 == q0) {
#pragma unroll
      for (int jt = 0; jt < 4; ++jt)
#pragma unroll
        for (int r = 0; r < 4; ++r) {
          int col = q0 + jt * 16 + m16;
          int row = qr0 + g * 4 + r;
          float p = __builtin_amdgcn_exp2f(S[jt][r] - SM_BIAS);
          p = (col <= row) ? p : 0.f;
          S[jt][r] = p;
          lrow[r] += p;
        }
    } else {
#pragma unroll
      for (int jt = 0; jt < 4; ++jt)
#pragma unroll
        for (int r = 0; r < 4; ++r) {
          float p = __builtin_amdgcn_exp2f(S[jt][r] - SM_BIAS);
          S[jt][r] = p;
          lrow[r] += p;
        }
    }
    // P -> per-wave Pt (transposed [key][qrow]): 4 vector b64 writes
#pragma unroll
    for (int jt = 0; jt < 4; ++jt) {
      ushort4 pw;
      pw.x = f2bf(S[jt][0]); pw.y = f2bf(S[jt][1]);
      pw.z = f2bf(S[jt][2]); pw.w = f2bf(S[jt][3]);
      *(ushort4*)&Pt[w][(jt * 16 + m16) * 16 + g * 4] = pw;
    }
    // A-fragment reload via hardware transpose read (lane stride 8 B in-group)
    s16x4 a0, a1, b0, b1;
    {
      __attribute__((address_space(3))) unsigned short* p3 =
          (__attribute__((address_space(3))) unsigned short*)&Pt[w][g * 128 + m16 * 4];
      unsigned paddr = (unsigned)(size_t)p3;
      asm volatile(
          "s_waitcnt lgkmcnt(0)\n\t"
          "ds_read_b64_tr_b16 %0, %4\n\t"
          "ds_read_b64_tr_b16 %1, %4 offset:128\n\t"
          "ds_read_b64_tr_b16 %2, %4 offset:1024\n\t"
          "ds_read_b64_tr_b16 %3, %4 offset:1152\n\t"
          "s_waitcnt lgkmcnt(0)"
          : "=&v"(a0), "=&v"(a1), "=&v"(b0), "=&v"(b1)
          : "v"(paddr)
          : "memory");
      __builtin_amdgcn_sched_barrier(0);  // rule #18: keep MFMAs below the wait
    }
    bf16x8 pf0 = __builtin_shufflevector(a0, a1, 0, 1, 2, 3, 4, 5, 6, 7);
    bf16x8 pf1 = __builtin_shufflevector(b0, b1, 0, 1, 2, 3, 4, 5, 6, 7);
    // O += P V
    __builtin_amdgcn_s_setprio(1);
#pragma unroll
    for (int dt = 0; dt < 4; ++dt) {
      const int rb = (dt * 16 + m16) * 64;
      bf16x8 vf0 = *(const bf16x8*)&VsB[rb + ((g * 8) ^ sw8)];
      bf16x8 vf1 = *(const bf16x8*)&VsB[rb + (((g + 4) * 8) ^ sw8)];
      Oacc[dt] = __builtin_amdgcn_mfma_f32_16x16x32_bf16(pf0, vf0, Oacc[dt], 0, 0, 0);
      Oacc[dt] = __builtin_amdgcn_mfma_f32_16x16x32_bf16(pf1, vf1, Oacc[dt], 0, 0, 0);
    }
    __builtin_amdgcn_s_setprio(0);
    // single barrier per tile: syncs waves AND drains prefetch vmcnt
    __syncthreads();
  }
  // epilogue: reduce l across the 16-lane column groups, normalize, store
  float inv[4];
#pragma unroll
  for (int r = 0; r < 4; ++r) {
#pragma unroll
    for (int off = 1; off < 16; off <<= 1) lrow[r] += __shfl_xor(lrow[r], off);
    inv[r] = 1.0f / lrow[r];
  }
#pragma unroll
  for (int dt = 0; dt < 4; ++dt)
#pragma unroll
    for (int r = 0; r < 4; ++r) {
      int row = qr0 + g * 4 + r;
      qkv[(size_t)(b * LL + row) * QS + h * 64 + dt * 16 + m16] = f2bf(Oacc[dt][r] * inv[r]);
    }
}

// ---------------------------------------------------------------------------
extern "C" void kernel_launch(void* const* d_in, const int* in_sizes, int n_in,
                              void* d_out, int out_size, void* d_ws, size_t ws_size,
                              hipStream_t stream) {
  const void* x = d_in[0];
  const void* cosp = d_in[1];
  const void* sinp = d_in[2];
  const void* Wq = d_in[3];
  const void* Wk = d_in[4];
  const void* Wv = d_in[5];
  const void* Wo = d_in[6];
  float* out = (float*)d_out;

  // ws (bf16): xb [4096][2048] | qkvb [4096][3072] | WqkvT [3072][2048]
  //          | WoT [2048][2048] | Vt [2*8][64][2048]
  char* w0 = (char*)d_ws;
  int* flags = (int*)w0;
  unsigned short* xb = (unsigned short*)(w0 + 256);
  unsigned short* qkvb = xb + (size_t)MM * 2048;
  unsigned short* WqkvT = qkvb + (size_t)MM * QS;
  unsigned short* WoT = WqkvT + (size_t)QS * 2048;
  unsigned short* vt = WoT + (size_t)2048 * 2048;

  detect_all<<<7, 256, 0, stream>>>(
      (const unsigned short*)x, (const unsigned short*)cosp, (const unsigned short*)sinp,
      (const unsigned short*)Wq, (const unsigned short*)Wk, (const unsigned short*)Wv,
      (const unsigned short*)Wo, flags);
  cvt_bf16<<<MM * 2048 / 4 / 256, 256, 0, stream>>>(x, xb, MM * 2048 / 4, flags, 0);
  transpose_all<<<dim3(32, 32, 4), 256, 0, stream>>>(Wq, Wk, Wv, Wo, WqkvT, WoT, flags);
  // fused QKV projection + RoPE/RMSNorm epilogue (q pre-scaled) + V^T to vt
  gemm_mfma<unsigned short, 1><<<dim3(QS / 128, MM / 128), 256, 0, stream>>>(
      xb, WqkvT, qkvb, MM, QS, 2048, 2048, cosp, sinp, flags, vt);
  // causal GQA attention, O in-place into q columns; longest qt first
  attn_mfma<<<dim3(NH, BB, LL / 64), 256, 0, stream>>>(qkvb, vt);
  // output projection: qkv's q columns (lda=3072) @ WoT -> f32 out
  gemm_mfma<float, 0><<<dim3(2048 / 128, MM / 128), 256, 0, stream>>>(
      qkvb, WoT, out, MM, 2048, 2048, QS, nullptr, nullptr, nullptr, nullptr);
}

// Round 8
// 342.265 us; speedup vs baseline: 1.0670x; 1.0670x over previous
//
#include <hip/hip_runtime.h>
#include <hip/hip_bf16.h>
#include <cstdint>
#include <cstddef>

#define D_MODEL 2048
#define NH 32
#define NKV 8
#define HD 64
#define BB 2
#define LL 2048
#define EPS 1e-6f
#define MM (BB * LL)   // 4096
#define QS 3072        // fused qkv row stride
#define KO 2048        // k column offset in qkv
#define VO 2560        // v column offset in qkv
// softmax fold: q pre-scaled by 0.125*log2(e); p = 2^(S - 8*log2(e))
#define QSCALE 0.18033688f
#define SM_BIAS 11.5415603f

typedef __hip_bfloat16 bf16;
typedef short bf16x8 __attribute__((ext_vector_type(8)));
typedef short s16x4 __attribute__((ext_vector_type(4)));
typedef float f32x4 __attribute__((ext_vector_type(4)));

// ---- dtype helpers ---------------------------------------------------------
__device__ inline float4 ld_bf4u(const unsigned short* p) {
  const ushort4 u = *(const ushort4*)p;
  float4 r;
  r.x = __uint_as_float(((unsigned)u.x) << 16);
  r.y = __uint_as_float(((unsigned)u.y) << 16);
  r.z = __uint_as_float(((unsigned)u.z) << 16);
  r.w = __uint_as_float(((unsigned)u.w) << 16);
  return r;
}
__device__ inline float4 ld4_rt(const void* p, size_t i, bool f32) {
  if (f32) return *(const float4*)((const float*)p + i);
  return ld_bf4u((const unsigned short*)p + i);
}
__device__ inline float ld1_rt(const void* p, size_t i, bool f32) {
  if (f32) return ((const float*)p)[i];
  unsigned short u = ((const unsigned short*)p)[i];
  return __uint_as_float(((unsigned)u) << 16);
}
__device__ inline unsigned short f2bf(float f) {
  bf16 h = __float2bfloat16(f);  // RNE
  return *reinterpret_cast<unsigned short*>(&h);
}
__device__ inline float bfu2f(unsigned short u) {
  return __uint_as_float(((unsigned)u) << 16);
}
__device__ inline void store1(float* p, float v) { *p = v; }
__device__ inline void store1(unsigned short* p, float v) { *p = f2bf(v); }

// async global->LDS, 16 B per lane; LDS dest must be wave-uniform base + lane*16
__device__ inline void glds16(const unsigned short* g, unsigned short* l) {
  __builtin_amdgcn_global_load_lds(
      (const __attribute__((address_space(1))) unsigned int*)g,
      (__attribute__((address_space(3))) unsigned int*)l, 16, 0, 0);
}

// ---- per-input dtype detector (sampled, vectorized) ------------------------
__global__ __launch_bounds__(256) void detect_all(
    const unsigned short* p0, const unsigned short* p1, const unsigned short* p2,
    const unsigned short* p3, const unsigned short* p4, const unsigned short* p5,
    const unsigned short* p6, int* __restrict__ flags) {
  const unsigned short* ptrs[7] = {p0, p1, p2, p3, p4, p5, p6};
  const int b = blockIdx.x;
  const uint4* p = (const uint4*)ptrs[b];  // 8 words per uint4
  __shared__ int found;
  if (threadIdx.x == 0) found = 0;
  __syncthreads();
  int loc = 0;
#pragma unroll
  for (int it = 0; it < 16; ++it) {
    uint4 v = p[it * 256 + threadIdx.x];
    unsigned wds[4] = {v.x, v.y, v.z, v.w};
#pragma unroll
    for (int q = 0; q < 4; ++q) {
      unsigned lo = wds[q] & 0xFFFFu, hi = wds[q] >> 16;
      if (((lo >> 7) & 0xFFu) == 0xFFu || ((hi >> 7) & 0xFFu) == 0xFFu) loc = 1;
    }
  }
  if (loc) atomicOr(&found, 1);
  __syncthreads();
  if (threadIdx.x == 0) flags[b] = found;
}

// ---- prep: elementwise convert to bf16 -------------------------------------
__global__ __launch_bounds__(256) void cvt_bf16(const void* __restrict__ src,
                                                unsigned short* __restrict__ dst,
                                                int n4, const int* __restrict__ flags, int idx) {
  const bool f32 = flags[idx] != 0;
  int i = blockIdx.x * 256 + threadIdx.x;
  if (i < n4) {
    float4 v = ld4_rt(src, (size_t)i * 4, f32);
    ushort4 o;
    o.x = f2bf(v.x); o.y = f2bf(v.y); o.z = f2bf(v.z); o.w = f2bf(v.w);
    *(ushort4*)&dst[(size_t)i * 4] = o;
  }
}

// ---- prep: all 4 weight transposes in one launch ---------------------------
__global__ __launch_bounds__(256) void transpose_all(
    const void* __restrict__ Wq, const void* __restrict__ Wk,
    const void* __restrict__ Wv, const void* __restrict__ Wo,
    unsigned short* __restrict__ WqkvT, unsigned short* __restrict__ WoT,
    const int* __restrict__ flags) {
  const int z = blockIdx.z;
  const void* srcs[4] = {Wq, Wk, Wv, Wo};
  unsigned short* dsts[4] = {WqkvT, WqkvT + (size_t)KO * 2048, WqkvT + (size_t)VO * 2048, WoT};
  const int Ns[4] = {2048, 512, 512, 2048};
  const int N = Ns[z];
  if (blockIdx.x * 64 >= N) return;
  const void* src = srcs[z];
  unsigned short* dst = dsts[z];
  const bool f32 = flags[3 + z] != 0;
  const int K = 2048;
  __shared__ unsigned short tile[64][65];
  const int t = threadIdx.x;
  const int n0 = blockIdx.x * 64, k0 = blockIdx.y * 64;
  const int cr = t >> 4, cc = (t & 15) * 4;
#pragma unroll
  for (int rr = 0; rr < 4; ++rr) {
    int row = rr * 16 + cr;
    float4 v = ld4_rt(src, (size_t)(k0 + row) * N + n0 + cc, f32);
    tile[row][cc + 0] = f2bf(v.x);
    tile[row][cc + 1] = f2bf(v.y);
    tile[row][cc + 2] = f2bf(v.z);
    tile[row][cc + 3] = f2bf(v.w);
  }
  __syncthreads();
#pragma unroll
  for (int rr = 0; rr < 4; ++rr) {
    int nrow = rr * 16 + cr;
    ushort4 o;
    o.x = tile[cc + 0][nrow];
    o.y = tile[cc + 1][nrow];
    o.z = tile[cc + 2][nrow];
    o.w = tile[cc + 3][nrow];
    *(ushort4*)&dst[(size_t)(n0 + nrow) * K + k0 + cc] = o;
  }
}

// ---------------------------------------------------------------------------
// MFMA GEMM, 64x128 tile (BM=64 x BN=128), 3-buffer counted-vmcnt pipeline
// (R5's proven structure; R7's register prefetch reverted -- it cost VGPR
// 72->120 and doubled FETCH). Smaller M-tile doubles/triples the grid:
// QKV 1536 blocks (6/CU queued), out 1024 (4/CU); LDS 36 KB -> 4 blocks/CU
// resident (was 3). Wave owns 32x64 output (acc[2][4]); BN=128 keeps each
// wave on one full 64-col head so the in-lane RoPE pairing is unchanged.
// STAGE = 3 glds16 (1 A + 2 B) -> counted wait vmcnt(3) (2 tiles in flight).
// LDS chunk swizzle (both-sides, rule #21): conflict-free (R5: conflicts=0);
// XOR keys depend only on row mod 16 -- identical formulas.
// FUSE=1: QKV epilogue: RoPE+RMSNorm on q/k heads (q pre-scaled by QSCALE);
// V heads written TRANSPOSED directly to vt[b][kvh][d][L].
// ---------------------------------------------------------------------------
template <typename CT, int FUSE>
__global__ __launch_bounds__(256) void gemm_mfma(const unsigned short* __restrict__ A,
                                                 const unsigned short* __restrict__ Bt,
                                                 CT* __restrict__ C,
                                                 int M, int N, int K, int lda,
                                                 const void* __restrict__ cosp,
                                                 const void* __restrict__ sinp,
                                                 const int* __restrict__ flags,
                                                 unsigned short* __restrict__ vt) {
  __shared__ __align__(16) unsigned short As[3][64 * 32];   // [64][32], chunk-swizzled
  __shared__ __align__(16) unsigned short Bs[3][128 * 32];  // [128][32], chunk-swizzled
  const int t = threadIdx.x;
  const int lane = t & 63, w = t >> 6;
  const int wm = (w >> 1) * 32, wn = (w & 1) * 64;
  const int g = lane >> 4, m16 = lane & 15;
  // XCD swizzle: blocks resident on one XCD get a contiguous chunk of work ids
  const int nwg = gridDim.x * gridDim.y;
  const int orig = blockIdx.y * gridDim.x + blockIdx.x;
  const int swz = (orig & 7) * (nwg >> 3) + (orig >> 3);
  const int m0 = (swz / gridDim.x) * 64, n0 = (swz % gridDim.x) * 128;
  // staged source chunk for this thread (inverse of the read-side XOR)
  const int csw = (t & 3) ^ ((t >> 3) & 3);
  const unsigned short* gA = &A[(size_t)(m0 + (t >> 2)) * lda + csw * 8];
  const unsigned short* gB = &Bt[(size_t)(n0 + (t >> 2)) * K + csw * 8];
  const int l8 = t * 8;
  // read-side swizzled chunk (shorts offset within a 32-short row)
  const int cs8 = (g ^ ((m16 >> 1) & 3)) * 8;
  f32x4 acc[2][4] = {};
  const int T = K >> 5;  // K/32 k-steps

#define STAGE(k0_, buf_)                                        \
  do {                                                          \
    glds16(gA + (k0_), &As[buf_][l8]);                          \
    glds16(gB + (k0_), &Bs[buf_][l8]);                          \
    glds16(gB + (size_t)64 * K + (k0_), &Bs[buf_][l8 + 2048]);  \
  } while (0)

  // prologue: tiles 0 and 1 in flight; wait tile 0 only
  STAGE(0, 0);
  STAGE(32, 1);
  asm volatile("s_waitcnt vmcnt(3)" ::: "memory");
  __builtin_amdgcn_s_barrier();

  int buf = 0;
  for (int tt = 0; tt < T; ++tt) {
    const int k0 = tt << 5;
    if (tt + 2 < T) {
      int nb = buf + 2; if (nb >= 3) nb -= 3;
      STAGE(k0 + 64, nb);
    }
    bf16x8 af[2], bfr[4];
#pragma unroll
    for (int i = 0; i < 2; ++i) af[i] = *(const bf16x8*)&As[buf][(wm + i * 16 + m16) * 32 + cs8];
#pragma unroll
    for (int j = 0; j < 4; ++j) bfr[j] = *(const bf16x8*)&Bs[buf][(wn + j * 16 + m16) * 32 + cs8];
#pragma unroll
    for (int i = 0; i < 2; ++i)
#pragma unroll
      for (int j = 0; j < 4; ++j)
        acc[i][j] = __builtin_amdgcn_mfma_f32_16x16x32_bf16(af[i], bfr[j], acc[i][j], 0, 0, 0);
    if (tt + 1 < T) {
      if (tt + 2 < T) asm volatile("s_waitcnt vmcnt(3)" ::: "memory");
      else            asm volatile("s_waitcnt vmcnt(0)" ::: "memory");
      __builtin_amdgcn_s_barrier();
    }
    ++buf; if (buf >= 3) buf = 0;
  }
#undef STAGE

  if constexpr (FUSE) {
    const int colbase = n0 + wn;          // 64-aligned -> exactly one head/wave
    if (colbase < VO) {                   // q or k head: RoPE + RMSNorm
      const bool cf = flags[1] != 0, sf = flags[2] != 0;
      const float post = (colbase < KO) ? QSCALE : 1.0f;  // q: fold softmax scale
#pragma unroll
      for (int i = 0; i < 2; ++i)
#pragma unroll
        for (int r = 0; r < 4; ++r) {
          const int row = m0 + wm + i * 16 + g * 4 + r;
          const int l = row & (LL - 1);
          const float c0 = ld1_rt(cosp, l * 32 + m16, cf);
          const float c1 = ld1_rt(cosp, l * 32 + 16 + m16, cf);
          const float s0 = ld1_rt(sinp, l * 32 + m16, sf);
          const float s1 = ld1_rt(sinp, l * 32 + 16 + m16, sf);
          const float x0 = acc[i][0][r], x1 = acc[i][1][r];
          const float x2 = acc[i][2][r], x3 = acc[i][3][r];
          const float r0 = x0 * c0 - x2 * s0;
          const float r1 = x1 * c1 - x3 * s1;
          const float r2 = x2 * c0 + x0 * s0;
          const float r3 = x3 * c1 + x1 * s1;
          float ss = r0 * r0 + r1 * r1 + r2 * r2 + r3 * r3;
#pragma unroll
          for (int off = 1; off < 16; off <<= 1) ss += __shfl_xor(ss, off);
          const float sc = rsqrtf(ss * (1.0f / HD) + EPS) * post;
          CT* cr = &C[(size_t)row * N + colbase + m16];
          store1(cr + 0, r0 * sc);
          store1(cr + 16, r1 * sc);
          store1(cr + 32, r2 * sc);
          store1(cr + 48, r3 * sc);
        }
    } else {
      // V head: write transposed into vt[b][kvh][d=64][L]
      const int bb = (m0 + wm) >> 11;            // row block's batch
      const int lb = (m0 + wm) & (LL - 1);       // row block's l base
      const int kvh = (colbase - VO) >> 6;
      unsigned short* vb = vt + (size_t)(bb * NKV + kvh) * 64 * LL;
#pragma unroll
      for (int j = 0; j < 4; ++j)
#pragma unroll
        for (int i = 0; i < 2; ++i) {
          ushort4 pw;
          pw.x = f2bf(acc[i][j][0]); pw.y = f2bf(acc[i][j][1]);
          pw.z = f2bf(acc[i][j][2]); pw.w = f2bf(acc[i][j][3]);
          *(ushort4*)&vb[(size_t)(j * 16 + m16) * LL + lb + i * 16 + g * 4] = pw;
        }
    }
    return;
  }
#pragma unroll
  for (int i = 0; i < 2; ++i)
#pragma unroll
    for (int j = 0; j < 4; ++j)
#pragma unroll
      for (int r = 0; r < 4; ++r) {
        int row = m0 + wm + i * 16 + g * 4 + r;
        int col = n0 + wn + j * 16 + m16;
        store1(&C[(size_t)row * N + col], acc[i][j][r]);
      }
}

// ---------------------------------------------------------------------------
// MFMA causal GQA flash attention with STATIC-MAX softmax (R7: setprio around
// MFMA clusters, native v_exp_f32).
// ---------------------------------------------------------------------------
__global__ __launch_bounds__(256) void attn_mfma(unsigned short* __restrict__ qkv,
                                                 const unsigned short* __restrict__ vt) {
  __shared__ __align__(16) unsigned short Ks[2][64 * 64];  // [key][d], chunk-swizzled
  __shared__ __align__(16) unsigned short Vs[2][64 * 64];  // [d][key], chunk-swizzled
  __shared__ __align__(16) unsigned short Pt[4][64 * 16];  // per-wave P^T [key][qrow]
  const int t = threadIdx.x, lane = t & 63, w = t >> 6;
  const int g = lane >> 4, m16 = lane & 15;
  const int h = blockIdx.x, b = blockIdx.y;
  const int qt = (LL / 64 - 1) - blockIdx.z;  // longest blocks dispatch first
  const int kvh = h >> 2;
  const int q0 = qt * 64, qr0 = q0 + w * 16;

  bf16x8 qf0, qf1;
  {
    const unsigned short* qrow = &qkv[(size_t)(b * LL + qr0 + m16) * QS + h * 64 + g * 8];
    qf0 = *(const bf16x8*)&qrow[0];
    qf1 = *(const bf16x8*)&qrow[32];
  }
  f32x4 Oacc[4] = {};
  float lrow[4] = {0.f, 0.f, 0.f, 0.f};

  const int lr = lane >> 3;            // row within the 8-row group
  const int lc = (lane & 7) ^ lr;      // swizzled source 16B chunk
  const unsigned short* gK = &qkv[(size_t)(b * LL) * QS + KO + kvh * 64 + lc * 8];
  const unsigned short* gV = &vt[((size_t)(b * NKV + kvh) * 64 + w * 16 + lr) * LL + lc * 8];
  const int dbase = w * 1024 + lane * 8;  // LDS dest (shorts): wave-linear
  const int nIter = q0 / 64 + 1;

  // prologue: stage tile 0 into buffer 0
#pragma unroll
  for (int c = 0; c < 2; ++c) {
    glds16(gK + (size_t)(w * 16 + c * 8 + lr) * QS, &Ks[0][dbase + c * 512]);
    glds16(gV + (size_t)c * 8 * LL, &Vs[0][dbase + c * 512]);
  }
  __syncthreads();  // vmcnt(0) drain included

  const int sw8 = (m16 & 7) * 8;  // read-side chunk swizzle (shorts)
  for (int it = 0; it < nIter; ++it) {
    const int j0 = it * 64;
    const int cur = it & 1;
    if (it + 1 < nIter) {  // prefetch next tile into the other buffer
      const int nj = j0 + 64;
#pragma unroll
      for (int c = 0; c < 2; ++c) {
        glds16(gK + (size_t)(nj + w * 16 + c * 8 + lr) * QS, &Ks[cur ^ 1][dbase + c * 512]);
        glds16(gV + (size_t)c * 8 * LL + nj, &Vs[cur ^ 1][dbase + c * 512]);
      }
    }
    const unsigned short* KsB = Ks[cur];
    const unsigned short* VsB = Vs[cur];

    // S = Q K^T
    f32x4 S[4];
    __builtin_amdgcn_s_setprio(1);
#pragma unroll
    for (int jt = 0; jt < 4; ++jt) {
      const int rb = (jt * 16 + m16) * 64;
      bf16x8 kf0 = *(const bf16x8*)&KsB[rb + ((g * 8) ^ sw8)];
      bf16x8 kf1 = *(const bf16x8*)&KsB[rb + (((g + 4) * 8) ^ sw8)];
      f32x4 z = {0.f, 0.f, 0.f, 0.f};
      z = __builtin_amdgcn_mfma_f32_16x16x32_bf16(qf0, kf0, z, 0, 0, 0);
      S[jt] = __builtin_amdgcn_mfma_f32_16x16x32_bf16(qf1, kf1, z, 0, 0, 0);
    }
    __builtin_amdgcn_s_setprio(0);
    // static-max softmax: p = 2^(S - SM_BIAS); mask only on the diagonal tile
    if (j0 == q0) {
#pragma unroll
      for (int jt = 0; jt < 4; ++jt)
#pragma unroll
        for (int r = 0; r < 4; ++r) {
          int col = q0 + jt * 16 + m16;
          int row = qr0 + g * 4 + r;
          float p = __builtin_amdgcn_exp2f(S[jt][r] - SM_BIAS);
          p = (col <= row) ? p : 0.f;
          S[jt][r] = p;
          lrow[r] += p;
        }
    } else {
#pragma unroll
      for (int jt = 0; jt < 4; ++jt)
#pragma unroll
        for (int r = 0; r < 4; ++r) {
          float p = __builtin_amdgcn_exp2f(S[jt][r] - SM_BIAS);
          S[jt][r] = p;
          lrow[r] += p;
        }
    }
    // P -> per-wave Pt (transposed [key][qrow]): 4 vector b64 writes
#pragma unroll
    for (int jt = 0; jt < 4; ++jt) {
      ushort4 pw;
      pw.x = f2bf(S[jt][0]); pw.y = f2bf(S[jt][1]);
      pw.z = f2bf(S[jt][2]); pw.w = f2bf(S[jt][3]);
      *(ushort4*)&Pt[w][(jt * 16 + m16) * 16 + g * 4] = pw;
    }
    // A-fragment reload via hardware transpose read (lane stride 8 B in-group)
    s16x4 a0, a1, b0, b1;
    {
      __attribute__((address_space(3))) unsigned short* p3 =
          (__attribute__((address_space(3))) unsigned short*)&Pt[w][g * 128 + m16 * 4];
      unsigned paddr = (unsigned)(size_t)p3;
      asm volatile(
          "s_waitcnt lgkmcnt(0)\n\t"
          "ds_read_b64_tr_b16 %0, %4\n\t"
          "ds_read_b64_tr_b16 %1, %4 offset:128\n\t"
          "ds_read_b64_tr_b16 %2, %4 offset:1024\n\t"
          "ds_read_b64_tr_b16 %3, %4 offset:1152\n\t"
          "s_waitcnt lgkmcnt(0)"
          : "=&v"(a0), "=&v"(a1), "=&v"(b0), "=&v"(b1)
          : "v"(paddr)
          : "memory");
      __builtin_amdgcn_sched_barrier(0);  // rule #18: keep MFMAs below the wait
    }
    bf16x8 pf0 = __builtin_shufflevector(a0, a1, 0, 1, 2, 3, 4, 5, 6, 7);
    bf16x8 pf1 = __builtin_shufflevector(b0, b1, 0, 1, 2, 3, 4, 5, 6, 7);
    // O += P V
    __builtin_amdgcn_s_setprio(1);
#pragma unroll
    for (int dt = 0; dt < 4; ++dt) {
      const int rb = (dt * 16 + m16) * 64;
      bf16x8 vf0 = *(const bf16x8*)&VsB[rb + ((g * 8) ^ sw8)];
      bf16x8 vf1 = *(const bf16x8*)&VsB[rb + (((g + 4) * 8) ^ sw8)];
      Oacc[dt] = __builtin_amdgcn_mfma_f32_16x16x32_bf16(pf0, vf0, Oacc[dt], 0, 0, 0);
      Oacc[dt] = __builtin_amdgcn_mfma_f32_16x16x32_bf16(pf1, vf1, Oacc[dt], 0, 0, 0);
    }
    __builtin_amdgcn_s_setprio(0);
    // single barrier per tile: syncs waves AND drains prefetch vmcnt
    __syncthreads();
  }
  // epilogue: reduce l across the 16-lane column groups, normalize, store
  float inv[4];
#pragma unroll
  for (int r = 0; r < 4; ++r) {
#pragma unroll
    for (int off = 1; off < 16; off <<= 1) lrow[r] += __shfl_xor(lrow[r], off);
    inv[r] = 1.0f / lrow[r];
  }
#pragma unroll
  for (int dt = 0; dt < 4; ++dt)
#pragma unroll
    for (int r = 0; r < 4; ++r) {
      int row = qr0 + g * 4 + r;
      qkv[(size_t)(b * LL + row) * QS + h * 64 + dt * 16 + m16] = f2bf(Oacc[dt][r] * inv[r]);
    }
}

// ---------------------------------------------------------------------------
extern "C" void kernel_launch(void* const* d_in, const int* in_sizes, int n_in,
                              void* d_out, int out_size, void* d_ws, size_t ws_size,
                              hipStream_t stream) {
  const void* x = d_in[0];
  const void* cosp = d_in[1];
  const void* sinp = d_in[2];
  const void* Wq = d_in[3];
  const void* Wk = d_in[4];
  const void* Wv = d_in[5];
  const void* Wo = d_in[6];
  float* out = (float*)d_out;

  // ws (bf16): xb [4096][2048] | qkvb [4096][3072] | WqkvT [3072][2048]
  //          | WoT [2048][2048] | Vt [2*8][64][2048]
  char* w0 = (char*)d_ws;
  int* flags = (int*)w0;
  unsigned short* xb = (unsigned short*)(w0 + 256);
  unsigned short* qkvb = xb + (size_t)MM * 2048;
  unsigned short* WqkvT = qkvb + (size_t)MM * QS;
  unsigned short* WoT = WqkvT + (size_t)QS * 2048;
  unsigned short* vt = WoT + (size_t)2048 * 2048;

  detect_all<<<7, 256, 0, stream>>>(
      (const unsigned short*)x, (const unsigned short*)cosp, (const unsigned short*)sinp,
      (const unsigned short*)Wq, (const unsigned short*)Wk, (const unsigned short*)Wv,
      (const unsigned short*)Wo, flags);
  cvt_bf16<<<MM * 2048 / 4 / 256, 256, 0, stream>>>(x, xb, MM * 2048 / 4, flags, 0);
  transpose_all<<<dim3(32, 32, 4), 256, 0, stream>>>(Wq, Wk, Wv, Wo, WqkvT, WoT, flags);
  // fused QKV projection + RoPE/RMSNorm epilogue (q pre-scaled) + V^T to vt
  gemm_mfma<unsigned short, 1><<<dim3(QS / 128, MM / 64), 256, 0, stream>>>(
      xb, WqkvT, qkvb, MM, QS, 2048, 2048, cosp, sinp, flags, vt);
  // causal GQA attention, O in-place into q columns; longest qt first
  attn_mfma<<<dim3(NH, BB, LL / 64), 256, 0, stream>>>(qkvb, vt);
  // output projection: qkv's q columns (lda=3072) @ WoT -> f32 out
  gemm_mfma<float, 0><<<dim3(2048 / 128, MM / 64), 256, 0, stream>>>(
      qkvb, WoT, out, MM, 2048, 2048, QS, nullptr, nullptr, nullptr, nullptr);
}

// Round 9
// 330.417 us; speedup vs baseline: 1.1052x; 1.0359x over previous
//
#include <hip/hip_runtime.h>
#include <hip/hip_bf16.h>
#include <cstdint>
#include <cstddef>

#define D_MODEL 2048
#define NH 32
#define NKV 8
#define HD 64
#define BB 2
#define LL 2048
#define EPS 1e-6f
#define MM (BB * LL)   // 4096
#define QS 3072        // fused qkv row stride
#define KO 2048        // k column offset in qkv
#define VO 2560        // v column offset in qkv
// softmax fold: q pre-scaled by 0.125*log2(e); p = 2^(S - 8*log2(e))
#define QSCALE 0.18033688f
#define SM_BIAS 11.5415603f

typedef __hip_bfloat16 bf16;
typedef short bf16x8 __attribute__((ext_vector_type(8)));
typedef short s16x4 __attribute__((ext_vector_type(4)));
typedef float f32x4 __attribute__((ext_vector_type(4)));

// ---- dtype helpers ---------------------------------------------------------
__device__ inline float4 ld_bf4u(const unsigned short* p) {
  const ushort4 u = *(const ushort4*)p;
  float4 r;
  r.x = __uint_as_float(((unsigned)u.x) << 16);
  r.y = __uint_as_float(((unsigned)u.y) << 16);
  r.z = __uint_as_float(((unsigned)u.z) << 16);
  r.w = __uint_as_float(((unsigned)u.w) << 16);
  return r;
}
__device__ inline float4 ld4_rt(const void* p, size_t i, bool f32) {
  if (f32) return *(const float4*)((const float*)p + i);
  return ld_bf4u((const unsigned short*)p + i);
}
__device__ inline float ld1_rt(const void* p, size_t i, bool f32) {
  if (f32) return ((const float*)p)[i];
  unsigned short u = ((const unsigned short*)p)[i];
  return __uint_as_float(((unsigned)u) << 16);
}
__device__ inline unsigned short f2bf(float f) {
  bf16 h = __float2bfloat16(f);  // RNE
  return *reinterpret_cast<unsigned short*>(&h);
}
__device__ inline float bfu2f(unsigned short u) {
  return __uint_as_float(((unsigned)u) << 16);
}
__device__ inline void store1(float* p, float v) { *p = v; }
__device__ inline void store1(unsigned short* p, float v) { *p = f2bf(v); }

// async global->LDS, 16 B per lane; LDS dest must be wave-uniform base + lane*16
__device__ inline void glds16(const unsigned short* g, unsigned short* l) {
  __builtin_amdgcn_global_load_lds(
      (const __attribute__((address_space(1))) unsigned int*)g,
      (__attribute__((address_space(3))) unsigned int*)l, 16, 0, 0);
}

// ---- per-input dtype detector (sampled, vectorized) ------------------------
__global__ __launch_bounds__(256) void detect_all(
    const unsigned short* p0, const unsigned short* p1, const unsigned short* p2,
    const unsigned short* p3, const unsigned short* p4, const unsigned short* p5,
    const unsigned short* p6, int* __restrict__ flags) {
  const unsigned short* ptrs[7] = {p0, p1, p2, p3, p4, p5, p6};
  const int b = blockIdx.x;
  const uint4* p = (const uint4*)ptrs[b];  // 8 words per uint4
  __shared__ int found;
  if (threadIdx.x == 0) found = 0;
  __syncthreads();
  int loc = 0;
#pragma unroll
  for (int it = 0; it < 16; ++it) {
    uint4 v = p[it * 256 + threadIdx.x];
    unsigned wds[4] = {v.x, v.y, v.z, v.w};
#pragma unroll
    for (int q = 0; q < 4; ++q) {
      unsigned lo = wds[q] & 0xFFFFu, hi = wds[q] >> 16;
      if (((lo >> 7) & 0xFFu) == 0xFFu || ((hi >> 7) & 0xFFu) == 0xFFu) loc = 1;
    }
  }
  if (loc) atomicOr(&found, 1);
  __syncthreads();
  if (threadIdx.x == 0) flags[b] = found;
}

// ---- prep: elementwise convert to bf16 -------------------------------------
__global__ __launch_bounds__(256) void cvt_bf16(const void* __restrict__ src,
                                                unsigned short* __restrict__ dst,
                                                int n4, const int* __restrict__ flags, int idx) {
  const bool f32 = flags[idx] != 0;
  int i = blockIdx.x * 256 + threadIdx.x;
  if (i < n4) {
    float4 v = ld4_rt(src, (size_t)i * 4, f32);
    ushort4 o;
    o.x = f2bf(v.x); o.y = f2bf(v.y); o.z = f2bf(v.z); o.w = f2bf(v.w);
    *(ushort4*)&dst[(size_t)i * 4] = o;
  }
}

// ---- prep: all 4 weight transposes in one launch ---------------------------
__global__ __launch_bounds__(256) void transpose_all(
    const void* __restrict__ Wq, const void* __restrict__ Wk,
    const void* __restrict__ Wv, const void* __restrict__ Wo,
    unsigned short* __restrict__ WqkvT, unsigned short* __restrict__ WoT,
    const int* __restrict__ flags) {
  const int z = blockIdx.z;
  const void* srcs[4] = {Wq, Wk, Wv, Wo};
  unsigned short* dsts[4] = {WqkvT, WqkvT + (size_t)KO * 2048, WqkvT + (size_t)VO * 2048, WoT};
  const int Ns[4] = {2048, 512, 512, 2048};
  const int N = Ns[z];
  if (blockIdx.x * 64 >= N) return;
  const void* src = srcs[z];
  unsigned short* dst = dsts[z];
  const bool f32 = flags[3 + z] != 0;
  const int K = 2048;
  __shared__ unsigned short tile[64][65];
  const int t = threadIdx.x;
  const int n0 = blockIdx.x * 64, k0 = blockIdx.y * 64;
  const int cr = t >> 4, cc = (t & 15) * 4;
#pragma unroll
  for (int rr = 0; rr < 4; ++rr) {
    int row = rr * 16 + cr;
    float4 v = ld4_rt(src, (size_t)(k0 + row) * N + n0 + cc, f32);
    tile[row][cc + 0] = f2bf(v.x);
    tile[row][cc + 1] = f2bf(v.y);
    tile[row][cc + 2] = f2bf(v.z);
    tile[row][cc + 3] = f2bf(v.w);
  }
  __syncthreads();
#pragma unroll
  for (int rr = 0; rr < 4; ++rr) {
    int nrow = rr * 16 + cr;
    ushort4 o;
    o.x = tile[cc + 0][nrow];
    o.y = tile[cc + 1][nrow];
    o.z = tile[cc + 2][nrow];
    o.w = tile[cc + 3][nrow];
    *(ushort4*)&dst[(size_t)(n0 + nrow) * K + k0 + cc] = o;
  }
}

// ---------------------------------------------------------------------------
// MFMA GEMM, 128x128 tile, 3-buffer counted-vmcnt pipeline (R5 exact: 81 us,
// conflicts=0, FETCH 58 MB -- the measured optimum of this family; R6-R8
// tile/schedule variants all regressed).
// FUSE=1: QKV epilogue: RoPE+RMSNorm on q/k heads (q pre-scaled by QSCALE);
// V heads written TRANSPOSED directly to vt[b][kvh][d][L].
// ---------------------------------------------------------------------------
template <typename CT, int FUSE>
__global__ __launch_bounds__(256) void gemm_mfma(const unsigned short* __restrict__ A,
                                                 const unsigned short* __restrict__ Bt,
                                                 CT* __restrict__ C,
                                                 int M, int N, int K, int lda,
                                                 const void* __restrict__ cosp,
                                                 const void* __restrict__ sinp,
                                                 const int* __restrict__ flags,
                                                 unsigned short* __restrict__ vt) {
  __shared__ __align__(16) unsigned short As[3][128 * 32];  // [128][32], chunk-swizzled
  __shared__ __align__(16) unsigned short Bs[3][128 * 32];
  const int t = threadIdx.x;
  const int lane = t & 63, w = t >> 6;
  const int wm = (w >> 1) * 64, wn = (w & 1) * 64;
  const int g = lane >> 4, m16 = lane & 15;
  // XCD swizzle: blocks resident on one XCD get a contiguous chunk of work ids
  const int nwg = gridDim.x * gridDim.y;
  const int orig = blockIdx.y * gridDim.x + blockIdx.x;
  const int swz = (orig & 7) * (nwg >> 3) + (orig >> 3);
  const int m0 = (swz / gridDim.x) * 128, n0 = (swz % gridDim.x) * 128;
  // staged source chunk for this thread (inverse of the read-side XOR)
  const int csw = (t & 3) ^ ((t >> 3) & 3);
  const unsigned short* gA = &A[(size_t)(m0 + (t >> 2)) * lda + csw * 8];
  const unsigned short* gB = &Bt[(size_t)(n0 + (t >> 2)) * K + csw * 8];
  const int l8 = t * 8;
  // read-side swizzled chunk (shorts offset within a 32-short row)
  const int cs8 = (g ^ ((m16 >> 1) & 3)) * 8;
  f32x4 acc[4][4] = {};
  const int T = K >> 5;  // K/32 k-steps

#define STAGE(k0_, buf_)                                        \
  do {                                                          \
    glds16(gA + (k0_), &As[buf_][l8]);                          \
    glds16(gA + (size_t)64 * lda + (k0_), &As[buf_][l8 + 2048]);\
    glds16(gB + (k0_), &Bs[buf_][l8]);                          \
    glds16(gB + (size_t)64 * K + (k0_), &Bs[buf_][l8 + 2048]);  \
  } while (0)

  // prologue: tiles 0 and 1 in flight; wait tile 0 only
  STAGE(0, 0);
  STAGE(32, 1);
  asm volatile("s_waitcnt vmcnt(4)" ::: "memory");
  __builtin_amdgcn_s_barrier();

  int buf = 0;
  for (int tt = 0; tt < T; ++tt) {
    const int k0 = tt << 5;
    if (tt + 2 < T) {
      int nb = buf + 2; if (nb >= 3) nb -= 3;
      STAGE(k0 + 64, nb);
    }
    bf16x8 af[4], bfr[4];
#pragma unroll
    for (int i = 0; i < 4; ++i) af[i] = *(const bf16x8*)&As[buf][(wm + i * 16 + m16) * 32 + cs8];
#pragma unroll
    for (int j = 0; j < 4; ++j) bfr[j] = *(const bf16x8*)&Bs[buf][(wn + j * 16 + m16) * 32 + cs8];
#pragma unroll
    for (int i = 0; i < 4; ++i)
#pragma unroll
      for (int j = 0; j < 4; ++j)
        acc[i][j] = __builtin_amdgcn_mfma_f32_16x16x32_bf16(af[i], bfr[j], acc[i][j], 0, 0, 0);
    if (tt + 1 < T) {
      if (tt + 2 < T) asm volatile("s_waitcnt vmcnt(4)" ::: "memory");
      else            asm volatile("s_waitcnt vmcnt(0)" ::: "memory");
      __builtin_amdgcn_s_barrier();
    }
    ++buf; if (buf >= 3) buf = 0;
  }
#undef STAGE

  if constexpr (FUSE) {
    const int colbase = n0 + wn;          // 64-aligned -> exactly one head/wave
    if (colbase < VO) {                   // q or k head: RoPE + RMSNorm
      const bool cf = flags[1] != 0, sf = flags[2] != 0;
      const float post = (colbase < KO) ? QSCALE : 1.0f;  // q: fold softmax scale
#pragma unroll
      for (int i = 0; i < 4; ++i)
#pragma unroll
        for (int r = 0; r < 4; ++r) {
          const int row = m0 + wm + i * 16 + g * 4 + r;
          const int l = row & (LL - 1);
          const float c0 = ld1_rt(cosp, l * 32 + m16, cf);
          const float c1 = ld1_rt(cosp, l * 32 + 16 + m16, cf);
          const float s0 = ld1_rt(sinp, l * 32 + m16, sf);
          const float s1 = ld1_rt(sinp, l * 32 + 16 + m16, sf);
          const float x0 = acc[i][0][r], x1 = acc[i][1][r];
          const float x2 = acc[i][2][r], x3 = acc[i][3][r];
          const float r0 = x0 * c0 - x2 * s0;
          const float r1 = x1 * c1 - x3 * s1;
          const float r2 = x2 * c0 + x0 * s0;
          const float r3 = x3 * c1 + x1 * s1;
          float ss = r0 * r0 + r1 * r1 + r2 * r2 + r3 * r3;
#pragma unroll
          for (int off = 1; off < 16; off <<= 1) ss += __shfl_xor(ss, off);
          const float sc = rsqrtf(ss * (1.0f / HD) + EPS) * post;
          CT* cr = &C[(size_t)row * N + colbase + m16];
          store1(cr + 0, r0 * sc);
          store1(cr + 16, r1 * sc);
          store1(cr + 32, r2 * sc);
          store1(cr + 48, r3 * sc);
        }
    } else {
      // V head: write transposed into vt[b][kvh][d=64][L]
      const int bb = (m0 + wm) >> 11;            // row block's batch
      const int lb = (m0 + wm) & (LL - 1);       // row block's l base
      const int kvh = (colbase - VO) >> 6;
      unsigned short* vb = vt + (size_t)(bb * NKV + kvh) * 64 * LL;
#pragma unroll
      for (int j = 0; j < 4; ++j)
#pragma unroll
        for (int i = 0; i < 4; ++i) {
          ushort4 pw;
          pw.x = f2bf(acc[i][j][0]); pw.y = f2bf(acc[i][j][1]);
          pw.z = f2bf(acc[i][j][2]); pw.w = f2bf(acc[i][j][3]);
          *(ushort4*)&vb[(size_t)(j * 16 + m16) * LL + lb + i * 16 + g * 4] = pw;
        }
    }
    return;
  }
#pragma unroll
  for (int i = 0; i < 4; ++i)
#pragma unroll
    for (int j = 0; j < 4; ++j)
#pragma unroll
      for (int r = 0; r < 4; ++r) {
        int row = m0 + wm + i * 16 + g * 4 + r;
        int col = n0 + wn + j * 16 + m16;
        store1(&C[(size_t)row * N + col], acc[i][j][r]);
      }
}

// ---------------------------------------------------------------------------
// MFMA causal GQA flash attention, GQA-factored: ONE BLOCK PER KV-HEAD
// (grid 8x2x32 = 512 blocks); wave w owns q-head kvh*4+w. K/V tiles are
// staged ONCE per block instead of once per q-head (4x less staging traffic
// and 4x fewer barrier-steps); each wave computes a full 64x64 q-tile:
// per KV tile 32 QK^T MFMA + 32 PV MFMA, S[4][4], per-row-tile softmax via
// the verified Pt/tr-read path (per-i 1 KB sub-regions, single lgkm
// round-trip for all 4 row-tiles). STATIC-MAX softmax: q pre-scaled by
// QSCALE => p = 2^(S - SM_BIAS), native v_exp_f32.
// ---------------------------------------------------------------------------
__global__ __launch_bounds__(256) void attn_mfma(unsigned short* __restrict__ qkv,
                                                 const unsigned short* __restrict__ vt) {
  __shared__ __align__(16) unsigned short Ks[2][64 * 64];  // [key][d], chunk-swizzled
  __shared__ __align__(16) unsigned short Vs[2][64 * 64];  // [d][key], chunk-swizzled
  __shared__ __align__(16) unsigned short Pt[4][64 * 64];  // per-wave P^T, 4x [key][qrow] sub-regions
  const int t = threadIdx.x, lane = t & 63, w = t >> 6;
  const int g = lane >> 4, m16 = lane & 15;
  const int kvh = blockIdx.x, b = blockIdx.y;
  const int qt = (LL / 64 - 1) - blockIdx.z;  // longest blocks dispatch first
  const int h = kvh * 4 + w;                  // this wave's q-head
  const int q0 = qt * 64;

  // Q fragments: 4 row-tiles x 2 k-halves, loaded once
  bf16x8 qf[4][2];
#pragma unroll
  for (int i = 0; i < 4; ++i) {
    const unsigned short* qrow = &qkv[(size_t)(b * LL + q0 + i * 16 + m16) * QS + h * 64 + g * 8];
    qf[i][0] = *(const bf16x8*)&qrow[0];
    qf[i][1] = *(const bf16x8*)&qrow[32];
  }
  f32x4 Oacc[4][4] = {};     // [row-tile][dt]
  float lrow[4][4] = {};     // [row-tile][r]

  // staging geometry (unchanged; kvh-indexed, wave-cooperative)
  const int lr = lane >> 3;            // row within the 8-row group
  const int lc = (lane & 7) ^ lr;      // swizzled source 16B chunk
  const unsigned short* gK = &qkv[(size_t)(b * LL) * QS + KO + kvh * 64 + lc * 8];
  const unsigned short* gV = &vt[((size_t)(b * NKV + kvh) * 64 + w * 16 + lr) * LL + lc * 8];
  const int dbase = w * 1024 + lane * 8;  // LDS dest (shorts): wave-linear
  const int nIter = q0 / 64 + 1;

  // prologue: stage tile 0 into buffer 0
#pragma unroll
  for (int c = 0; c < 2; ++c) {
    glds16(gK + (size_t)(w * 16 + c * 8 + lr) * QS, &Ks[0][dbase + c * 512]);
    glds16(gV + (size_t)c * 8 * LL, &Vs[0][dbase + c * 512]);
  }
  __syncthreads();  // vmcnt(0) drain included

  const int sw8 = (m16 & 7) * 8;  // read-side chunk swizzle (shorts)
  for (int it = 0; it < nIter; ++it) {
    const int j0 = it * 64;
    const int cur = it & 1;
    if (it + 1 < nIter) {  // prefetch next tile into the other buffer
      const int nj = j0 + 64;
#pragma unroll
      for (int c = 0; c < 2; ++c) {
        glds16(gK + (size_t)(nj + w * 16 + c * 8 + lr) * QS, &Ks[cur ^ 1][dbase + c * 512]);
        glds16(gV + (size_t)c * 8 * LL + nj, &Vs[cur ^ 1][dbase + c * 512]);
      }
    }
    const unsigned short* KsB = Ks[cur];
    const unsigned short* VsB = Vs[cur];

    // S = Q K^T for all 4 row-tiles (K frags read once, reused 4x)
    f32x4 S[4][4];
    __builtin_amdgcn_s_setprio(1);
#pragma unroll
    for (int jt = 0; jt < 4; ++jt) {
      const int rb = (jt * 16 + m16) * 64;
      bf16x8 kf0 = *(const bf16x8*)&KsB[rb + ((g * 8) ^ sw8)];
      bf16x8 kf1 = *(const bf16x8*)&KsB[rb + (((g + 4) * 8) ^ sw8)];
#pragma unroll
      for (int i = 0; i < 4; ++i) {
        f32x4 z = {0.f, 0.f, 0.f, 0.f};
        z = __builtin_amdgcn_mfma_f32_16x16x32_bf16(qf[i][0], kf0, z, 0, 0, 0);
        S[i][jt] = __builtin_amdgcn_mfma_f32_16x16x32_bf16(qf[i][1], kf1, z, 0, 0, 0);
      }
    }
    __builtin_amdgcn_s_setprio(0);
    // static-max softmax + P^T writes (per row-tile sub-region of Pt[w])
    if (j0 == q0) {
#pragma unroll
      for (int i = 0; i < 4; ++i)
#pragma unroll
        for (int jt = 0; jt < 4; ++jt)
#pragma unroll
          for (int r = 0; r < 4; ++r) {
            int col = q0 + jt * 16 + m16;
            int row = q0 + i * 16 + g * 4 + r;
            float p = __builtin_amdgcn_exp2f(S[i][jt][r] - SM_BIAS);
            p = (col <= row) ? p : 0.f;
            S[i][jt][r] = p;
            lrow[i][r] += p;
          }
    } else {
#pragma unroll
      for (int i = 0; i < 4; ++i)
#pragma unroll
        for (int jt = 0; jt < 4; ++jt)
#pragma unroll
          for (int r = 0; r < 4; ++r) {
            float p = __builtin_amdgcn_exp2f(S[i][jt][r] - SM_BIAS);
            S[i][jt][r] = p;
            lrow[i][r] += p;
          }
    }
#pragma unroll
    for (int i = 0; i < 4; ++i)
#pragma unroll
      for (int jt = 0; jt < 4; ++jt) {
        ushort4 pw;
        pw.x = f2bf(S[i][jt][0]); pw.y = f2bf(S[i][jt][1]);
        pw.z = f2bf(S[i][jt][2]); pw.w = f2bf(S[i][jt][3]);
        *(ushort4*)&Pt[w][i * 1024 + (jt * 16 + m16) * 16 + g * 4] = pw;
      }
    // A-fragment reload via hardware transpose read: one lgkm round-trip
    // for all 4 row-tiles (16 tr reads issued back-to-back)
    s16x4 ta[4], tb[4], tc[4], td[4];
    asm volatile("s_waitcnt lgkmcnt(0)" ::: "memory");
#pragma unroll
    for (int i = 0; i < 4; ++i) {
      __attribute__((address_space(3))) unsigned short* p3 =
          (__attribute__((address_space(3))) unsigned short*)&Pt[w][i * 1024 + g * 128 + m16 * 4];
      unsigned paddr = (unsigned)(size_t)p3;
      asm volatile(
          "ds_read_b64_tr_b16 %0, %4\n\t"
          "ds_read_b64_tr_b16 %1, %4 offset:128\n\t"
          "ds_read_b64_tr_b16 %2, %4 offset:1024\n\t"
          "ds_read_b64_tr_b16 %3, %4 offset:1152"
          : "=&v"(ta[i]), "=&v"(tb[i]), "=&v"(tc[i]), "=&v"(td[i])
          : "v"(paddr));
    }
    asm volatile("s_waitcnt lgkmcnt(0)" ::: "memory");
    __builtin_amdgcn_sched_barrier(0);  // rule #18: keep MFMAs below the wait
    bf16x8 pf[4][2];
#pragma unroll
    for (int i = 0; i < 4; ++i) {
      pf[i][0] = __builtin_shufflevector(ta[i], tb[i], 0, 1, 2, 3, 4, 5, 6, 7);
      pf[i][1] = __builtin_shufflevector(tc[i], td[i], 0, 1, 2, 3, 4, 5, 6, 7);
    }
    // O += P V (V frags read once per dt, reused 4x)
    __builtin_amdgcn_s_setprio(1);
#pragma unroll
    for (int dt = 0; dt < 4; ++dt) {
      const int rb = (dt * 16 + m16) * 64;
      bf16x8 vf0 = *(const bf16x8*)&VsB[rb + ((g * 8) ^ sw8)];
      bf16x8 vf1 = *(const bf16x8*)&VsB[rb + (((g + 4) * 8) ^ sw8)];
#pragma unroll
      for (int i = 0; i < 4; ++i) {
        Oacc[i][dt] = __builtin_amdgcn_mfma_f32_16x16x32_bf16(pf[i][0], vf0, Oacc[i][dt], 0, 0, 0);
        Oacc[i][dt] = __builtin_amdgcn_mfma_f32_16x16x32_bf16(pf[i][1], vf1, Oacc[i][dt], 0, 0, 0);
      }
    }
    __builtin_amdgcn_s_setprio(0);
    // single barrier per tile: syncs waves AND drains prefetch vmcnt
    __syncthreads();
  }
  // epilogue: per row-tile, reduce l across 16-lane column groups, store
#pragma unroll
  for (int i = 0; i < 4; ++i) {
    float inv[4];
#pragma unroll
    for (int r = 0; r < 4; ++r) {
#pragma unroll
      for (int off = 1; off < 16; off <<= 1) lrow[i][r] += __shfl_xor(lrow[i][r], off);
      inv[r] = 1.0f / lrow[i][r];
    }
#pragma unroll
    for (int dt = 0; dt < 4; ++dt)
#pragma unroll
      for (int r = 0; r < 4; ++r) {
        int row = q0 + i * 16 + g * 4 + r;
        qkv[(size_t)(b * LL + row) * QS + h * 64 + dt * 16 + m16] = f2bf(Oacc[i][dt][r] * inv[r]);
      }
  }
}

// ---------------------------------------------------------------------------
extern "C" void kernel_launch(void* const* d_in, const int* in_sizes, int n_in,
                              void* d_out, int out_size, void* d_ws, size_t ws_size,
                              hipStream_t stream) {
  const void* x = d_in[0];
  const void* cosp = d_in[1];
  const void* sinp = d_in[2];
  const void* Wq = d_in[3];
  const void* Wk = d_in[4];
  const void* Wv = d_in[5];
  const void* Wo = d_in[6];
  float* out = (float*)d_out;

  // ws (bf16): xb [4096][2048] | qkvb [4096][3072] | WqkvT [3072][2048]
  //          | WoT [2048][2048] | Vt [2*8][64][2048]
  char* w0 = (char*)d_ws;
  int* flags = (int*)w0;
  unsigned short* xb = (unsigned short*)(w0 + 256);
  unsigned short* qkvb = xb + (size_t)MM * 2048;
  unsigned short* WqkvT = qkvb + (size_t)MM * QS;
  unsigned short* WoT = WqkvT + (size_t)QS * 2048;
  unsigned short* vt = WoT + (size_t)2048 * 2048;

  detect_all<<<7, 256, 0, stream>>>(
      (const unsigned short*)x, (const unsigned short*)cosp, (const unsigned short*)sinp,
      (const unsigned short*)Wq, (const unsigned short*)Wk, (const unsigned short*)Wv,
      (const unsigned short*)Wo, flags);
  cvt_bf16<<<MM * 2048 / 4 / 256, 256, 0, stream>>>(x, xb, MM * 2048 / 4, flags, 0);
  transpose_all<<<dim3(32, 32, 4), 256, 0, stream>>>(Wq, Wk, Wv, Wo, WqkvT, WoT, flags);
  // fused QKV projection + RoPE/RMSNorm epilogue (q pre-scaled) + V^T to vt
  gemm_mfma<unsigned short, 1><<<dim3(QS / 128, MM / 128), 256, 0, stream>>>(
      xb, WqkvT, qkvb, MM, QS, 2048, 2048, cosp, sinp, flags, vt);
  // causal GQA attention, one block per kv-head; longest qt first
  attn_mfma<<<dim3(NKV, BB, LL / 64), 256, 0, stream>>>(qkvb, vt);
  // output projection: qkv's q columns (lda=3072) @ WoT -> f32 out
  gemm_mfma<float, 0><<<dim3(2048 / 128, MM / 128), 256, 0, stream>>>(
      qkvb, WoT, out, MM, 2048, 2048, QS, nullptr, nullptr, nullptr, nullptr);
}

// Round 10
// 309.727 us; speedup vs baseline: 1.1791x; 1.0668x over previous
//
#include <hip/hip_runtime.h>
#include <hip/hip_bf16.h>
#include <cstdint>
#include <cstddef>

#define D_MODEL 2048
#define NH 32
#define NKV 8
#define HD 64
#define BB 2
#define LL 2048
#define EPS 1e-6f
#define MM (BB * LL)   // 4096
#define QS 3072        // fused qkv row stride
#define KO 2048        // k column offset in qkv
#define VO 2560        // v column offset in qkv
// softmax fold: q pre-scaled by 0.125*log2(e) in the GEMM epilogue.
// attn computes p = 2^S DIRECTLY (no bias subtract): S <= 11.6 => p <= 3100,
// no overflow, and the 2^-bias factor cancels in PV / l.
#define QSCALE 0.18033688f

typedef __hip_bfloat16 bf16;
typedef short bf16x8 __attribute__((ext_vector_type(8)));
typedef short s16x4 __attribute__((ext_vector_type(4)));
typedef float f32x4 __attribute__((ext_vector_type(4)));

// ---- dtype helpers ---------------------------------------------------------
__device__ inline float4 ld_bf4u(const unsigned short* p) {
  const ushort4 u = *(const ushort4*)p;
  float4 r;
  r.x = __uint_as_float(((unsigned)u.x) << 16);
  r.y = __uint_as_float(((unsigned)u.y) << 16);
  r.z = __uint_as_float(((unsigned)u.z) << 16);
  r.w = __uint_as_float(((unsigned)u.w) << 16);
  return r;
}
__device__ inline float4 ld4_rt(const void* p, size_t i, bool f32) {
  if (f32) return *(const float4*)((const float*)p + i);
  return ld_bf4u((const unsigned short*)p + i);
}
__device__ inline float ld1_rt(const void* p, size_t i, bool f32) {
  if (f32) return ((const float*)p)[i];
  unsigned short u = ((const unsigned short*)p)[i];
  return __uint_as_float(((unsigned)u) << 16);
}
__device__ inline unsigned short f2bf(float f) {
  bf16 h = __float2bfloat16(f);  // RNE
  return *reinterpret_cast<unsigned short*>(&h);
}
__device__ inline float bfu2f(unsigned short u) {
  return __uint_as_float(((unsigned)u) << 16);
}
__device__ inline void store1(float* p, float v) { *p = v; }
__device__ inline void store1(unsigned short* p, float v) { *p = f2bf(v); }

// async global->LDS, 16 B per lane; LDS dest must be wave-uniform base + lane*16
__device__ inline void glds16(const unsigned short* g, unsigned short* l) {
  __builtin_amdgcn_global_load_lds(
      (const __attribute__((address_space(1))) unsigned int*)g,
      (__attribute__((address_space(3))) unsigned int*)l, 16, 0, 0);
}

// ---- per-input dtype detector (sampled, vectorized) ------------------------
__global__ __launch_bounds__(256) void detect_all(
    const unsigned short* p0, const unsigned short* p1, const unsigned short* p2,
    const unsigned short* p3, const unsigned short* p4, const unsigned short* p5,
    const unsigned short* p6, int* __restrict__ flags) {
  const unsigned short* ptrs[7] = {p0, p1, p2, p3, p4, p5, p6};
  const int b = blockIdx.x;
  const uint4* p = (const uint4*)ptrs[b];  // 8 words per uint4
  __shared__ int found;
  if (threadIdx.x == 0) found = 0;
  __syncthreads();
  int loc = 0;
#pragma unroll
  for (int it = 0; it < 16; ++it) {
    uint4 v = p[it * 256 + threadIdx.x];
    unsigned wds[4] = {v.x, v.y, v.z, v.w};
#pragma unroll
    for (int q = 0; q < 4; ++q) {
      unsigned lo = wds[q] & 0xFFFFu, hi = wds[q] >> 16;
      if (((lo >> 7) & 0xFFu) == 0xFFu || ((hi >> 7) & 0xFFu) == 0xFFu) loc = 1;
    }
  }
  if (loc) atomicOr(&found, 1);
  __syncthreads();
  if (threadIdx.x == 0) flags[b] = found;
}

// ---- prep: elementwise convert to bf16 -------------------------------------
__global__ __launch_bounds__(256) void cvt_bf16(const void* __restrict__ src,
                                                unsigned short* __restrict__ dst,
                                                int n4, const int* __restrict__ flags, int idx) {
  const bool f32 = flags[idx] != 0;
  int i = blockIdx.x * 256 + threadIdx.x;
  if (i < n4) {
    float4 v = ld4_rt(src, (size_t)i * 4, f32);
    ushort4 o;
    o.x = f2bf(v.x); o.y = f2bf(v.y); o.z = f2bf(v.z); o.w = f2bf(v.w);
    *(ushort4*)&dst[(size_t)i * 4] = o;
  }
}

// ---- prep: all 4 weight transposes in one launch ---------------------------
__global__ __launch_bounds__(256) void transpose_all(
    const void* __restrict__ Wq, const void* __restrict__ Wk,
    const void* __restrict__ Wv, const void* __restrict__ Wo,
    unsigned short* __restrict__ WqkvT, unsigned short* __restrict__ WoT,
    const int* __restrict__ flags) {
  const int z = blockIdx.z;
  const void* srcs[4] = {Wq, Wk, Wv, Wo};
  unsigned short* dsts[4] = {WqkvT, WqkvT + (size_t)KO * 2048, WqkvT + (size_t)VO * 2048, WoT};
  const int Ns[4] = {2048, 512, 512, 2048};
  const int N = Ns[z];
  if (blockIdx.x * 64 >= N) return;
  const void* src = srcs[z];
  unsigned short* dst = dsts[z];
  const bool f32 = flags[3 + z] != 0;
  const int K = 2048;
  __shared__ unsigned short tile[64][65];
  const int t = threadIdx.x;
  const int n0 = blockIdx.x * 64, k0 = blockIdx.y * 64;
  const int cr = t >> 4, cc = (t & 15) * 4;
#pragma unroll
  for (int rr = 0; rr < 4; ++rr) {
    int row = rr * 16 + cr;
    float4 v = ld4_rt(src, (size_t)(k0 + row) * N + n0 + cc, f32);
    tile[row][cc + 0] = f2bf(v.x);
    tile[row][cc + 1] = f2bf(v.y);
    tile[row][cc + 2] = f2bf(v.z);
    tile[row][cc + 3] = f2bf(v.w);
  }
  __syncthreads();
#pragma unroll
  for (int rr = 0; rr < 4; ++rr) {
    int nrow = rr * 16 + cr;
    ushort4 o;
    o.x = tile[cc + 0][nrow];
    o.y = tile[cc + 1][nrow];
    o.z = tile[cc + 2][nrow];
    o.w = tile[cc + 3][nrow];
    *(ushort4*)&dst[(size_t)(n0 + nrow) * K + k0 + cc] = o;
  }
}

// ---------------------------------------------------------------------------
// MFMA GEMM, 128x128 tile, 3-buffer counted-vmcnt pipeline (R5 exact: 81 us,
// conflicts=0, FETCH 58 MB -- the measured optimum of this family).
// FUSE=1: QKV epilogue: RoPE+RMSNorm on q/k heads (q pre-scaled by QSCALE);
// V heads written TRANSPOSED directly to vt[b][kvh][d][L].
// ---------------------------------------------------------------------------
template <typename CT, int FUSE>
__global__ __launch_bounds__(256) void gemm_mfma(const unsigned short* __restrict__ A,
                                                 const unsigned short* __restrict__ Bt,
                                                 CT* __restrict__ C,
                                                 int M, int N, int K, int lda,
                                                 const void* __restrict__ cosp,
                                                 const void* __restrict__ sinp,
                                                 const int* __restrict__ flags,
                                                 unsigned short* __restrict__ vt) {
  __shared__ __align__(16) unsigned short As[3][128 * 32];  // [128][32], chunk-swizzled
  __shared__ __align__(16) unsigned short Bs[3][128 * 32];
  const int t = threadIdx.x;
  const int lane = t & 63, w = t >> 6;
  const int wm = (w >> 1) * 64, wn = (w & 1) * 64;
  const int g = lane >> 4, m16 = lane & 15;
  // XCD swizzle: blocks resident on one XCD get a contiguous chunk of work ids
  const int nwg = gridDim.x * gridDim.y;
  const int orig = blockIdx.y * gridDim.x + blockIdx.x;
  const int swz = (orig & 7) * (nwg >> 3) + (orig >> 3);
  const int m0 = (swz / gridDim.x) * 128, n0 = (swz % gridDim.x) * 128;
  // staged source chunk for this thread (inverse of the read-side XOR)
  const int csw = (t & 3) ^ ((t >> 3) & 3);
  const unsigned short* gA = &A[(size_t)(m0 + (t >> 2)) * lda + csw * 8];
  const unsigned short* gB = &Bt[(size_t)(n0 + (t >> 2)) * K + csw * 8];
  const int l8 = t * 8;
  // read-side swizzled chunk (shorts offset within a 32-short row)
  const int cs8 = (g ^ ((m16 >> 1) & 3)) * 8;
  f32x4 acc[4][4] = {};
  const int T = K >> 5;  // K/32 k-steps

#define STAGE(k0_, buf_)                                        \
  do {                                                          \
    glds16(gA + (k0_), &As[buf_][l8]);                          \
    glds16(gA + (size_t)64 * lda + (k0_), &As[buf_][l8 + 2048]);\
    glds16(gB + (k0_), &Bs[buf_][l8]);                          \
    glds16(gB + (size_t)64 * K + (k0_), &Bs[buf_][l8 + 2048]);  \
  } while (0)

  // prologue: tiles 0 and 1 in flight; wait tile 0 only
  STAGE(0, 0);
  STAGE(32, 1);
  asm volatile("s_waitcnt vmcnt(4)" ::: "memory");
  __builtin_amdgcn_s_barrier();

  int buf = 0;
  for (int tt = 0; tt < T; ++tt) {
    const int k0 = tt << 5;
    if (tt + 2 < T) {
      int nb = buf + 2; if (nb >= 3) nb -= 3;
      STAGE(k0 + 64, nb);
    }
    bf16x8 af[4], bfr[4];
#pragma unroll
    for (int i = 0; i < 4; ++i) af[i] = *(const bf16x8*)&As[buf][(wm + i * 16 + m16) * 32 + cs8];
#pragma unroll
    for (int j = 0; j < 4; ++j) bfr[j] = *(const bf16x8*)&Bs[buf][(wn + j * 16 + m16) * 32 + cs8];
#pragma unroll
    for (int i = 0; i < 4; ++i)
#pragma unroll
      for (int j = 0; j < 4; ++j)
        acc[i][j] = __builtin_amdgcn_mfma_f32_16x16x32_bf16(af[i], bfr[j], acc[i][j], 0, 0, 0);
    if (tt + 1 < T) {
      if (tt + 2 < T) asm volatile("s_waitcnt vmcnt(4)" ::: "memory");
      else            asm volatile("s_waitcnt vmcnt(0)" ::: "memory");
      __builtin_amdgcn_s_barrier();
    }
    ++buf; if (buf >= 3) buf = 0;
  }
#undef STAGE

  if constexpr (FUSE) {
    const int colbase = n0 + wn;          // 64-aligned -> exactly one head/wave
    if (colbase < VO) {                   // q or k head: RoPE + RMSNorm
      const bool cf = flags[1] != 0, sf = flags[2] != 0;
      const float post = (colbase < KO) ? QSCALE : 1.0f;  // q: fold softmax scale
#pragma unroll
      for (int i = 0; i < 4; ++i)
#pragma unroll
        for (int r = 0; r < 4; ++r) {
          const int row = m0 + wm + i * 16 + g * 4 + r;
          const int l = row & (LL - 1);
          const float c0 = ld1_rt(cosp, l * 32 + m16, cf);
          const float c1 = ld1_rt(cosp, l * 32 + 16 + m16, cf);
          const float s0 = ld1_rt(sinp, l * 32 + m16, sf);
          const float s1 = ld1_rt(sinp, l * 32 + 16 + m16, sf);
          const float x0 = acc[i][0][r], x1 = acc[i][1][r];
          const float x2 = acc[i][2][r], x3 = acc[i][3][r];
          const float r0 = x0 * c0 - x2 * s0;
          const float r1 = x1 * c1 - x3 * s1;
          const float r2 = x2 * c0 + x0 * s0;
          const float r3 = x3 * c1 + x1 * s1;
          float ss = r0 * r0 + r1 * r1 + r2 * r2 + r3 * r3;
#pragma unroll
          for (int off = 1; off < 16; off <<= 1) ss += __shfl_xor(ss, off);
          const float sc = rsqrtf(ss * (1.0f / HD) + EPS) * post;
          CT* cr = &C[(size_t)row * N + colbase + m16];
          store1(cr + 0, r0 * sc);
          store1(cr + 16, r1 * sc);
          store1(cr + 32, r2 * sc);
          store1(cr + 48, r3 * sc);
        }
    } else {
      // V head: write transposed into vt[b][kvh][d=64][L]
      const int bb = (m0 + wm) >> 11;            // row block's batch
      const int lb = (m0 + wm) & (LL - 1);       // row block's l base
      const int kvh = (colbase - VO) >> 6;
      unsigned short* vb = vt + (size_t)(bb * NKV + kvh) * 64 * LL;
#pragma unroll
      for (int j = 0; j < 4; ++j)
#pragma unroll
        for (int i = 0; i < 4; ++i) {
          ushort4 pw;
          pw.x = f2bf(acc[i][j][0]); pw.y = f2bf(acc[i][j][1]);
          pw.z = f2bf(acc[i][j][2]); pw.w = f2bf(acc[i][j][3]);
          *(ushort4*)&vb[(size_t)(j * 16 + m16) * LL + lb + i * 16 + g * 4] = pw;
        }
    }
    return;
  }
#pragma unroll
  for (int i = 0; i < 4; ++i)
#pragma unroll
    for (int j = 0; j < 4; ++j)
#pragma unroll
      for (int r = 0; r < 4; ++r) {
        int row = m0 + wm + i * 16 + g * 4 + r;
        int col = n0 + wn + j * 16 + m16;
        store1(&C[(size_t)row * N + col], acc[i][j][r]);
      }
}

// ---------------------------------------------------------------------------
// MFMA causal GQA flash attention, per-q-head blocks (2048 blocks -- R9's
// kv-head factoring collapsed occupancy to 10% and is reverted).
// VALU-reduction round: (1) p = 2^S directly (bias cancels in PV/l; -16 sub
// per tile); (2) l accumulated by MFMA with a B==1.0 fragment -- D[row][*] =
// sum_k P[row][k] has the SAME row mapping as Oacc, so inv[r]=1/lacc[r] and
// the 16-lane shfl epilogue disappears (-16 add/tile, -16 shfl; +2 MFMA on a
// 13%-busy pipe).
// ---------------------------------------------------------------------------
__global__ __launch_bounds__(256) void attn_mfma(unsigned short* __restrict__ qkv,
                                                 const unsigned short* __restrict__ vt) {
  __shared__ __align__(16) unsigned short Ks[2][64 * 64];  // [key][d], chunk-swizzled
  __shared__ __align__(16) unsigned short Vs[2][64 * 64];  // [d][key], chunk-swizzled
  __shared__ __align__(16) unsigned short Pt[4][64 * 16];  // per-wave P^T [key][qrow]
  const int t = threadIdx.x, lane = t & 63, w = t >> 6;
  const int g = lane >> 4, m16 = lane & 15;
  const int h = blockIdx.x, b = blockIdx.y;
  const int qt = (LL / 64 - 1) - blockIdx.z;  // longest blocks dispatch first
  const int kvh = h >> 2;
  const int q0 = qt * 64, qr0 = q0 + w * 16;

  bf16x8 qf0, qf1;
  {
    const unsigned short* qrow = &qkv[(size_t)(b * LL + qr0 + m16) * QS + h * 64 + g * 8];
    qf0 = *(const bf16x8*)&qrow[0];
    qf1 = *(const bf16x8*)&qrow[32];
  }
  f32x4 Oacc[4] = {};
  f32x4 lacc = {0.f, 0.f, 0.f, 0.f};
  const short one_bf = (short)0x3F80;  // bf16 1.0
  const bf16x8 ones = {one_bf, one_bf, one_bf, one_bf, one_bf, one_bf, one_bf, one_bf};

  const int lr = lane >> 3;            // row within the 8-row group
  const int lc = (lane & 7) ^ lr;      // swizzled source 16B chunk
  const unsigned short* gK = &qkv[(size_t)(b * LL) * QS + KO + kvh * 64 + lc * 8];
  const unsigned short* gV = &vt[((size_t)(b * NKV + kvh) * 64 + w * 16 + lr) * LL + lc * 8];
  const int dbase = w * 1024 + lane * 8;  // LDS dest (shorts): wave-linear
  const int nIter = q0 / 64 + 1;

  // prologue: stage tile 0 into buffer 0
#pragma unroll
  for (int c = 0; c < 2; ++c) {
    glds16(gK + (size_t)(w * 16 + c * 8 + lr) * QS, &Ks[0][dbase + c * 512]);
    glds16(gV + (size_t)c * 8 * LL, &Vs[0][dbase + c * 512]);
  }
  __syncthreads();  // vmcnt(0) drain included

  const int sw8 = (m16 & 7) * 8;  // read-side chunk swizzle (shorts)
  for (int it = 0; it < nIter; ++it) {
    const int j0 = it * 64;
    const int cur = it & 1;
    if (it + 1 < nIter) {  // prefetch next tile into the other buffer
      const int nj = j0 + 64;
#pragma unroll
      for (int c = 0; c < 2; ++c) {
        glds16(gK + (size_t)(nj + w * 16 + c * 8 + lr) * QS, &Ks[cur ^ 1][dbase + c * 512]);
        glds16(gV + (size_t)c * 8 * LL + nj, &Vs[cur ^ 1][dbase + c * 512]);
      }
    }
    const unsigned short* KsB = Ks[cur];
    const unsigned short* VsB = Vs[cur];

    // S = Q K^T
    f32x4 S[4];
    __builtin_amdgcn_s_setprio(1);
#pragma unroll
    for (int jt = 0; jt < 4; ++jt) {
      const int rb = (jt * 16 + m16) * 64;
      bf16x8 kf0 = *(const bf16x8*)&KsB[rb + ((g * 8) ^ sw8)];
      bf16x8 kf1 = *(const bf16x8*)&KsB[rb + (((g + 4) * 8) ^ sw8)];
      f32x4 z = {0.f, 0.f, 0.f, 0.f};
      z = __builtin_amdgcn_mfma_f32_16x16x32_bf16(qf0, kf0, z, 0, 0, 0);
      S[jt] = __builtin_amdgcn_mfma_f32_16x16x32_bf16(qf1, kf1, z, 0, 0, 0);
    }
    __builtin_amdgcn_s_setprio(0);
    // softmax numerator: p = 2^S (no bias; cancels in PV/l). Mask on diag tile.
    if (j0 == q0) {
#pragma unroll
      for (int jt = 0; jt < 4; ++jt)
#pragma unroll
        for (int r = 0; r < 4; ++r) {
          int col = q0 + jt * 16 + m16;
          int row = qr0 + g * 4 + r;
          float p = __builtin_amdgcn_exp2f(S[jt][r]);
          S[jt][r] = (col <= row) ? p : 0.f;
        }
    } else {
#pragma unroll
      for (int jt = 0; jt < 4; ++jt)
#pragma unroll
        for (int r = 0; r < 4; ++r)
          S[jt][r] = __builtin_amdgcn_exp2f(S[jt][r]);
    }
    // P -> per-wave Pt (transposed [key][qrow]): 4 vector b64 writes
#pragma unroll
    for (int jt = 0; jt < 4; ++jt) {
      ushort4 pw;
      pw.x = f2bf(S[jt][0]); pw.y = f2bf(S[jt][1]);
      pw.z = f2bf(S[jt][2]); pw.w = f2bf(S[jt][3]);
      *(ushort4*)&Pt[w][(jt * 16 + m16) * 16 + g * 4] = pw;
    }
    // A-fragment reload via hardware transpose read (lane stride 8 B in-group)
    s16x4 a0, a1, b0, b1;
    {
      __attribute__((address_space(3))) unsigned short* p3 =
          (__attribute__((address_space(3))) unsigned short*)&Pt[w][g * 128 + m16 * 4];
      unsigned paddr = (unsigned)(size_t)p3;
      asm volatile(
          "s_waitcnt lgkmcnt(0)\n\t"
          "ds_read_b64_tr_b16 %0, %4\n\t"
          "ds_read_b64_tr_b16 %1, %4 offset:128\n\t"
          "ds_read_b64_tr_b16 %2, %4 offset:1024\n\t"
          "ds_read_b64_tr_b16 %3, %4 offset:1152\n\t"
          "s_waitcnt lgkmcnt(0)"
          : "=&v"(a0), "=&v"(a1), "=&v"(b0), "=&v"(b1)
          : "v"(paddr)
          : "memory");
      __builtin_amdgcn_sched_barrier(0);  // rule #18: keep MFMAs below the wait
    }
    bf16x8 pf0 = __builtin_shufflevector(a0, a1, 0, 1, 2, 3, 4, 5, 6, 7);
    bf16x8 pf1 = __builtin_shufflevector(b0, b1, 0, 1, 2, 3, 4, 5, 6, 7);
    // O += P V ; l += P @ 1 (row-sum via matrix pipe)
    __builtin_amdgcn_s_setprio(1);
    lacc = __builtin_amdgcn_mfma_f32_16x16x32_bf16(pf0, ones, lacc, 0, 0, 0);
    lacc = __builtin_amdgcn_mfma_f32_16x16x32_bf16(pf1, ones, lacc, 0, 0, 0);
#pragma unroll
    for (int dt = 0; dt < 4; ++dt) {
      const int rb = (dt * 16 + m16) * 64;
      bf16x8 vf0 = *(const bf16x8*)&VsB[rb + ((g * 8) ^ sw8)];
      bf16x8 vf1 = *(const bf16x8*)&VsB[rb + (((g + 4) * 8) ^ sw8)];
      Oacc[dt] = __builtin_amdgcn_mfma_f32_16x16x32_bf16(pf0, vf0, Oacc[dt], 0, 0, 0);
      Oacc[dt] = __builtin_amdgcn_mfma_f32_16x16x32_bf16(pf1, vf1, Oacc[dt], 0, 0, 0);
    }
    __builtin_amdgcn_s_setprio(0);
    // single barrier per tile: syncs waves AND drains prefetch vmcnt
    __syncthreads();
  }
  // epilogue: lacc[r] already holds the full row sum (MFMA summed over keys)
  float inv[4];
#pragma unroll
  for (int r = 0; r < 4; ++r) inv[r] = 1.0f / lacc[r];
#pragma unroll
  for (int dt = 0; dt < 4; ++dt)
#pragma unroll
    for (int r = 0; r < 4; ++r) {
      int row = qr0 + g * 4 + r;
      qkv[(size_t)(b * LL + row) * QS + h * 64 + dt * 16 + m16] = f2bf(Oacc[dt][r] * inv[r]);
    }
}

// ---------------------------------------------------------------------------
extern "C" void kernel_launch(void* const* d_in, const int* in_sizes, int n_in,
                              void* d_out, int out_size, void* d_ws, size_t ws_size,
                              hipStream_t stream) {
  const void* x = d_in[0];
  const void* cosp = d_in[1];
  const void* sinp = d_in[2];
  const void* Wq = d_in[3];
  const void* Wk = d_in[4];
  const void* Wv = d_in[5];
  const void* Wo = d_in[6];
  float* out = (float*)d_out;

  // ws (bf16): xb [4096][2048] | qkvb [4096][3072] | WqkvT [3072][2048]
  //          | WoT [2048][2048] | Vt [2*8][64][2048]
  char* w0 = (char*)d_ws;
  int* flags = (int*)w0;
  unsigned short* xb = (unsigned short*)(w0 + 256);
  unsigned short* qkvb = xb + (size_t)MM * 2048;
  unsigned short* WqkvT = qkvb + (size_t)MM * QS;
  unsigned short* WoT = WqkvT + (size_t)QS * 2048;
  unsigned short* vt = WoT + (size_t)2048 * 2048;

  detect_all<<<7, 256, 0, stream>>>(
      (const unsigned short*)x, (const unsigned short*)cosp, (const unsigned short*)sinp,
      (const unsigned short*)Wq, (const unsigned short*)Wk, (const unsigned short*)Wv,
      (const unsigned short*)Wo, flags);
  cvt_bf16<<<MM * 2048 / 4 / 256, 256, 0, stream>>>(x, xb, MM * 2048 / 4, flags, 0);
  transpose_all<<<dim3(32, 32, 4), 256, 0, stream>>>(Wq, Wk, Wv, Wo, WqkvT, WoT, flags);
  // fused QKV projection + RoPE/RMSNorm epilogue (q pre-scaled) + V^T to vt
  gemm_mfma<unsigned short, 1><<<dim3(QS / 128, MM / 128), 256, 0, stream>>>(
      xb, WqkvT, qkvb, MM, QS, 2048, 2048, cosp, sinp, flags, vt);
  // causal GQA attention, O in-place into q columns; longest qt first
  attn_mfma<<<dim3(NH, BB, LL / 64), 256, 0, stream>>>(qkvb, vt);
  // output projection: qkv's q columns (lda=3072) @ WoT -> f32 out
  gemm_mfma<float, 0><<<dim3(2048 / 128, MM / 128), 256, 0, stream>>>(
      qkvb, WoT, out, MM, 2048, 2048, QS, nullptr, nullptr, nullptr, nullptr);
}

// Round 11
// 296.981 us; speedup vs baseline: 1.2297x; 1.0429x over previous
//
#include <hip/hip_runtime.h>
#include <hip/hip_bf16.h>
#include <cstdint>
#include <cstddef>

#define D_MODEL 2048
#define NH 32
#define NKV 8
#define HD 64
#define BB 2
#define LL 2048
#define EPS 1e-6f
#define MM (BB * LL)   // 4096
#define QS 3072        // fused qkv row stride
#define KO 2048        // k column offset in qkv
#define VO 2560        // v column offset in qkv
// softmax fold: q pre-scaled by 0.125*log2(e) in the GEMM epilogue.
// attn computes p = 2^S DIRECTLY (no bias subtract): S <= 11.6 => p <= 3100,
// no overflow, and the 2^-bias factor cancels in PV / l.
#define QSCALE 0.18033688f

typedef __hip_bfloat16 bf16;
typedef short bf16x8 __attribute__((ext_vector_type(8)));
typedef short s16x4 __attribute__((ext_vector_type(4)));
typedef float f32x4 __attribute__((ext_vector_type(4)));

// ---- dtype helpers ---------------------------------------------------------
__device__ inline float4 ld_bf4u(const unsigned short* p) {
  const ushort4 u = *(const ushort4*)p;
  float4 r;
  r.x = __uint_as_float(((unsigned)u.x) << 16);
  r.y = __uint_as_float(((unsigned)u.y) << 16);
  r.z = __uint_as_float(((unsigned)u.z) << 16);
  r.w = __uint_as_float(((unsigned)u.w) << 16);
  return r;
}
__device__ inline float4 ld4_rt(const void* p, size_t i, bool f32) {
  if (f32) return *(const float4*)((const float*)p + i);
  return ld_bf4u((const unsigned short*)p + i);
}
__device__ inline float ld1_rt(const void* p, size_t i, bool f32) {
  if (f32) return ((const float*)p)[i];
  unsigned short u = ((const unsigned short*)p)[i];
  return __uint_as_float(((unsigned)u) << 16);
}
__device__ inline unsigned short f2bf(float f) {
  bf16 h = __float2bfloat16(f);  // RNE
  return *reinterpret_cast<unsigned short*>(&h);
}
__device__ inline float bfu2f(unsigned short u) {
  return __uint_as_float(((unsigned)u) << 16);
}
__device__ inline void store1(float* p, float v) { *p = v; }
__device__ inline void store1(unsigned short* p, float v) { *p = f2bf(v); }

// async global->LDS, 16 B per lane; LDS dest must be wave-uniform base + lane*16
__device__ inline void glds16(const unsigned short* g, unsigned short* l) {
  __builtin_amdgcn_global_load_lds(
      (const __attribute__((address_space(1))) unsigned int*)g,
      (__attribute__((address_space(3))) unsigned int*)l, 16, 0, 0);
}

// ---- per-input dtype detector (sampled, vectorized) ------------------------
__global__ __launch_bounds__(256) void detect_all(
    const unsigned short* p0, const unsigned short* p1, const unsigned short* p2,
    const unsigned short* p3, const unsigned short* p4, const unsigned short* p5,
    const unsigned short* p6, int* __restrict__ flags) {
  const unsigned short* ptrs[7] = {p0, p1, p2, p3, p4, p5, p6};
  const int b = blockIdx.x;
  const uint4* p = (const uint4*)ptrs[b];  // 8 words per uint4
  __shared__ int found;
  if (threadIdx.x == 0) found = 0;
  __syncthreads();
  int loc = 0;
#pragma unroll
  for (int it = 0; it < 16; ++it) {
    uint4 v = p[it * 256 + threadIdx.x];
    unsigned wds[4] = {v.x, v.y, v.z, v.w};
#pragma unroll
    for (int q = 0; q < 4; ++q) {
      unsigned lo = wds[q] & 0xFFFFu, hi = wds[q] >> 16;
      if (((lo >> 7) & 0xFFu) == 0xFFu || ((hi >> 7) & 0xFFu) == 0xFFu) loc = 1;
    }
  }
  if (loc) atomicOr(&found, 1);
  __syncthreads();
  if (threadIdx.x == 0) flags[b] = found;
}

// ---- prep: cvt x->bf16 AND all 4 weight transposes in ONE launch -----------
// blocks [0, 8192): cvt (x is MM*2048 = 8M elems, 4/thread).
// blocks [8192, 10752): transposes; sub-ranges z0 Wq 1024, z1 Wk 256,
// z2 Wv 256, z3 Wo 1024 blocks.
__global__ __launch_bounds__(256) void prep_all(
    const void* __restrict__ x, unsigned short* __restrict__ xb,
    const void* __restrict__ Wq, const void* __restrict__ Wk,
    const void* __restrict__ Wv, const void* __restrict__ Wo,
    unsigned short* __restrict__ WqkvT, unsigned short* __restrict__ WoT,
    const int* __restrict__ flags) {
  const int bid = blockIdx.x;
  const int t = threadIdx.x;
  if (bid < 8192) {
    const bool f32 = flags[0] != 0;
    int i = bid * 256 + t;
    float4 v = ld4_rt(x, (size_t)i * 4, f32);
    ushort4 o;
    o.x = f2bf(v.x); o.y = f2bf(v.y); o.z = f2bf(v.z); o.w = f2bf(v.w);
    *(ushort4*)&xb[(size_t)i * 4] = o;
    return;
  }
  int r = bid - 8192;
  int z, bx, by;
  if (r < 1024)      { z = 0; bx = r & 31; by = r >> 5; }
  else if (r < 1280) { z = 1; r -= 1024; bx = r & 7; by = r >> 3; }
  else if (r < 1536) { z = 2; r -= 1280; bx = r & 7; by = r >> 3; }
  else               { z = 3; r -= 1536; bx = r & 31; by = r >> 5; }
  const void* srcs[4] = {Wq, Wk, Wv, Wo};
  unsigned short* dsts[4] = {WqkvT, WqkvT + (size_t)KO * 2048, WqkvT + (size_t)VO * 2048, WoT};
  const int Ns[4] = {2048, 512, 512, 2048};
  const int N = Ns[z];
  const void* src = srcs[z];
  unsigned short* dst = dsts[z];
  const bool f32 = flags[3 + z] != 0;
  const int K = 2048;
  __shared__ unsigned short tile[64][65];
  const int n0 = bx * 64, k0 = by * 64;
  const int cr = t >> 4, cc = (t & 15) * 4;
#pragma unroll
  for (int rr = 0; rr < 4; ++rr) {
    int row = rr * 16 + cr;
    float4 v = ld4_rt(src, (size_t)(k0 + row) * N + n0 + cc, f32);
    tile[row][cc + 0] = f2bf(v.x);
    tile[row][cc + 1] = f2bf(v.y);
    tile[row][cc + 2] = f2bf(v.z);
    tile[row][cc + 3] = f2bf(v.w);
  }
  __syncthreads();
#pragma unroll
  for (int rr = 0; rr < 4; ++rr) {
    int nrow = rr * 16 + cr;
    ushort4 o;
    o.x = tile[cc + 0][nrow];
    o.y = tile[cc + 1][nrow];
    o.z = tile[cc + 2][nrow];
    o.w = tile[cc + 3][nrow];
    *(ushort4*)&dst[(size_t)(n0 + nrow) * K + k0 + cc] = o;
  }
}

// ---------------------------------------------------------------------------
// MFMA GEMM, 128x128 tile, 3-buffer counted-vmcnt pipeline (R5 exact: 80 us,
// conflicts=0, FETCH 58 MB -- the measured optimum of this family over 6
// structural variants; LDS-BW arithmetic puts this near its floor).
// FUSE=1: QKV epilogue: RoPE+RMSNorm on q/k heads (q pre-scaled by QSCALE);
// V heads written TRANSPOSED directly to vt[b][kvh][d][L].
// ---------------------------------------------------------------------------
template <typename CT, int FUSE>
__global__ __launch_bounds__(256) void gemm_mfma(const unsigned short* __restrict__ A,
                                                 const unsigned short* __restrict__ Bt,
                                                 CT* __restrict__ C,
                                                 int M, int N, int K, int lda,
                                                 const void* __restrict__ cosp,
                                                 const void* __restrict__ sinp,
                                                 const int* __restrict__ flags,
                                                 unsigned short* __restrict__ vt) {
  __shared__ __align__(16) unsigned short As[3][128 * 32];  // [128][32], chunk-swizzled
  __shared__ __align__(16) unsigned short Bs[3][128 * 32];
  const int t = threadIdx.x;
  const int lane = t & 63, w = t >> 6;
  const int wm = (w >> 1) * 64, wn = (w & 1) * 64;
  const int g = lane >> 4, m16 = lane & 15;
  // XCD swizzle: blocks resident on one XCD get a contiguous chunk of work ids
  const int nwg = gridDim.x * gridDim.y;
  const int orig = blockIdx.y * gridDim.x + blockIdx.x;
  const int swz = (orig & 7) * (nwg >> 3) + (orig >> 3);
  const int m0 = (swz / gridDim.x) * 128, n0 = (swz % gridDim.x) * 128;
  // staged source chunk for this thread (inverse of the read-side XOR)
  const int csw = (t & 3) ^ ((t >> 3) & 3);
  const unsigned short* gA = &A[(size_t)(m0 + (t >> 2)) * lda + csw * 8];
  const unsigned short* gB = &Bt[(size_t)(n0 + (t >> 2)) * K + csw * 8];
  const int l8 = t * 8;
  // read-side swizzled chunk (shorts offset within a 32-short row)
  const int cs8 = (g ^ ((m16 >> 1) & 3)) * 8;
  f32x4 acc[4][4] = {};
  const int T = K >> 5;  // K/32 k-steps

#define STAGE(k0_, buf_)                                        \
  do {                                                          \
    glds16(gA + (k0_), &As[buf_][l8]);                          \
    glds16(gA + (size_t)64 * lda + (k0_), &As[buf_][l8 + 2048]);\
    glds16(gB + (k0_), &Bs[buf_][l8]);                          \
    glds16(gB + (size_t)64 * K + (k0_), &Bs[buf_][l8 + 2048]);  \
  } while (0)

  // prologue: tiles 0 and 1 in flight; wait tile 0 only
  STAGE(0, 0);
  STAGE(32, 1);
  asm volatile("s_waitcnt vmcnt(4)" ::: "memory");
  __builtin_amdgcn_s_barrier();

  int buf = 0;
  for (int tt = 0; tt < T; ++tt) {
    const int k0 = tt << 5;
    if (tt + 2 < T) {
      int nb = buf + 2; if (nb >= 3) nb -= 3;
      STAGE(k0 + 64, nb);
    }
    bf16x8 af[4], bfr[4];
#pragma unroll
    for (int i = 0; i < 4; ++i) af[i] = *(const bf16x8*)&As[buf][(wm + i * 16 + m16) * 32 + cs8];
#pragma unroll
    for (int j = 0; j < 4; ++j) bfr[j] = *(const bf16x8*)&Bs[buf][(wn + j * 16 + m16) * 32 + cs8];
#pragma unroll
    for (int i = 0; i < 4; ++i)
#pragma unroll
      for (int j = 0; j < 4; ++j)
        acc[i][j] = __builtin_amdgcn_mfma_f32_16x16x32_bf16(af[i], bfr[j], acc[i][j], 0, 0, 0);
    if (tt + 1 < T) {
      if (tt + 2 < T) asm volatile("s_waitcnt vmcnt(4)" ::: "memory");
      else            asm volatile("s_waitcnt vmcnt(0)" ::: "memory");
      __builtin_amdgcn_s_barrier();
    }
    ++buf; if (buf >= 3) buf = 0;
  }
#undef STAGE

  if constexpr (FUSE) {
    const int colbase = n0 + wn;          // 64-aligned -> exactly one head/wave
    if (colbase < VO) {                   // q or k head: RoPE + RMSNorm
      const bool cf = flags[1] != 0, sf = flags[2] != 0;
      const float post = (colbase < KO) ? QSCALE : 1.0f;  // q: fold softmax scale
#pragma unroll
      for (int i = 0; i < 4; ++i)
#pragma unroll
        for (int r = 0; r < 4; ++r) {
          const int row = m0 + wm + i * 16 + g * 4 + r;
          const int l = row & (LL - 1);
          const float c0 = ld1_rt(cosp, l * 32 + m16, cf);
          const float c1 = ld1_rt(cosp, l * 32 + 16 + m16, cf);
          const float s0 = ld1_rt(sinp, l * 32 + m16, sf);
          const float s1 = ld1_rt(sinp, l * 32 + 16 + m16, sf);
          const float x0 = acc[i][0][r], x1 = acc[i][1][r];
          const float x2 = acc[i][2][r], x3 = acc[i][3][r];
          const float r0 = x0 * c0 - x2 * s0;
          const float r1 = x1 * c1 - x3 * s1;
          const float r2 = x2 * c0 + x0 * s0;
          const float r3 = x3 * c1 + x1 * s1;
          float ss = r0 * r0 + r1 * r1 + r2 * r2 + r3 * r3;
#pragma unroll
          for (int off = 1; off < 16; off <<= 1) ss += __shfl_xor(ss, off);
          const float sc = rsqrtf(ss * (1.0f / HD) + EPS) * post;
          CT* cr = &C[(size_t)row * N + colbase + m16];
          store1(cr + 0, r0 * sc);
          store1(cr + 16, r1 * sc);
          store1(cr + 32, r2 * sc);
          store1(cr + 48, r3 * sc);
        }
    } else {
      // V head: write transposed into vt[b][kvh][d=64][L]
      const int bb = (m0 + wm) >> 11;            // row block's batch
      const int lb = (m0 + wm) & (LL - 1);       // row block's l base
      const int kvh = (colbase - VO) >> 6;
      unsigned short* vb = vt + (size_t)(bb * NKV + kvh) * 64 * LL;
#pragma unroll
      for (int j = 0; j < 4; ++j)
#pragma unroll
        for (int i = 0; i < 4; ++i) {
          ushort4 pw;
          pw.x = f2bf(acc[i][j][0]); pw.y = f2bf(acc[i][j][1]);
          pw.z = f2bf(acc[i][j][2]); pw.w = f2bf(acc[i][j][3]);
          *(ushort4*)&vb[(size_t)(j * 16 + m16) * LL + lb + i * 16 + g * 4] = pw;
        }
    }
    return;
  }
#pragma unroll
  for (int i = 0; i < 4; ++i)
#pragma unroll
    for (int j = 0; j < 4; ++j)
#pragma unroll
      for (int r = 0; r < 4; ++r) {
        int row = m0 + wm + i * 16 + g * 4 + r;
        int col = n0 + wn + j * 16 + m16;
        store1(&C[(size_t)row * N + col], acc[i][j][r]);
      }
}

// ---------------------------------------------------------------------------
// MFMA causal GQA flash attention, QBLK=128 (8 waves, 512 thr): one block
// covers 128 q-rows, so K/V staging + barriers are amortized over 2x the
// work (total staged tiles 528 -> 272 per (h,b)) and occupancy rises
// (LDS 48 KB -> 3 blocks x 8 waves = 24 waves/CU vs 16). Wave w owns rows
// q0+w*16; its diagonal tile dtile = q0+(w>>2)*64; tiles j0>dtile skip
// compute (wave-uniform branch; barrier outside). Staging: 8 waves x 8 rows
// each (XOR chunk swizzle unchanged: row&7 == lr).
// p = 2^S direct; l via MFMA ones-column (R10, verified).
// ---------------------------------------------------------------------------
__global__ __launch_bounds__(512) void attn_mfma(unsigned short* __restrict__ qkv,
                                                 const unsigned short* __restrict__ vt) {
  __shared__ __align__(16) unsigned short Ks[2][64 * 64];  // [key][d], chunk-swizzled
  __shared__ __align__(16) unsigned short Vs[2][64 * 64];  // [d][key], chunk-swizzled
  __shared__ __align__(16) unsigned short Pt[8][64 * 16];  // per-wave P^T [key][qrow]
  const int t = threadIdx.x, lane = t & 63, w = t >> 6;    // w in 0..7
  const int g = lane >> 4, m16 = lane & 15;
  const int h = blockIdx.x, b = blockIdx.y;
  const int qt = (LL / 128 - 1) - blockIdx.z;  // longest blocks dispatch first
  const int kvh = h >> 2;
  const int q0 = qt * 128, qr0 = q0 + w * 16;
  const int dtile = q0 + ((w >> 2) << 6);      // this wave's diagonal KV tile

  bf16x8 qf0, qf1;
  {
    const unsigned short* qrow = &qkv[(size_t)(b * LL + qr0 + m16) * QS + h * 64 + g * 8];
    qf0 = *(const bf16x8*)&qrow[0];
    qf1 = *(const bf16x8*)&qrow[32];
  }
  f32x4 Oacc[4] = {};
  f32x4 lacc = {0.f, 0.f, 0.f, 0.f};
  const short one_bf = (short)0x3F80;  // bf16 1.0
  const bf16x8 ones = {one_bf, one_bf, one_bf, one_bf, one_bf, one_bf, one_bf, one_bf};

  // staging: 8 waves x 8 rows each (1 K glds16 + 1 V glds16 per wave per tile)
  const int lr = lane >> 3;            // row within the wave's 8-row group
  const int lc = (lane & 7) ^ lr;      // swizzled source 16B chunk
  const unsigned short* gK = &qkv[(size_t)(b * LL + w * 8 + lr) * QS + KO + kvh * 64 + lc * 8];
  const unsigned short* gV = &vt[((size_t)(b * NKV + kvh) * 64 + w * 8 + lr) * LL + lc * 8];
  const int dbase = w * 512 + lane * 8;  // LDS dest (shorts): wave-linear
  const int nIter = q0 / 64 + 2;         // KV tiles 0 .. q0+64

  // prologue: stage tile 0 into buffer 0
  glds16(gK, &Ks[0][dbase]);
  glds16(gV, &Vs[0][dbase]);
  __syncthreads();  // vmcnt(0) drain included

  const int sw8 = (m16 & 7) * 8;  // read-side chunk swizzle (shorts)
  for (int it = 0; it < nIter; ++it) {
    const int j0 = it * 64;
    const int cur = it & 1;
    if (it + 1 < nIter) {  // prefetch next tile into the other buffer
      const int nj = j0 + 64;
      glds16(gK + (size_t)nj * QS, &Ks[cur ^ 1][dbase]);
      glds16(gV + nj, &Vs[cur ^ 1][dbase]);
    }
    if (j0 <= dtile) {  // wave-uniform: skip tiles above this wave's diagonal
      const unsigned short* KsB = Ks[cur];
      const unsigned short* VsB = Vs[cur];

      // S = Q K^T
      f32x4 S[4];
      __builtin_amdgcn_s_setprio(1);
#pragma unroll
      for (int jt = 0; jt < 4; ++jt) {
        const int rb = (jt * 16 + m16) * 64;
        bf16x8 kf0 = *(const bf16x8*)&KsB[rb + ((g * 8) ^ sw8)];
        bf16x8 kf1 = *(const bf16x8*)&KsB[rb + (((g + 4) * 8) ^ sw8)];
        f32x4 z = {0.f, 0.f, 0.f, 0.f};
        z = __builtin_amdgcn_mfma_f32_16x16x32_bf16(qf0, kf0, z, 0, 0, 0);
        S[jt] = __builtin_amdgcn_mfma_f32_16x16x32_bf16(qf1, kf1, z, 0, 0, 0);
      }
      __builtin_amdgcn_s_setprio(0);
      // softmax numerator: p = 2^S. Mask on this wave's diagonal tile.
      if (j0 == dtile) {
#pragma unroll
        for (int jt = 0; jt < 4; ++jt)
#pragma unroll
          for (int r = 0; r < 4; ++r) {
            int col = j0 + jt * 16 + m16;
            int row = qr0 + g * 4 + r;
            float p = __builtin_amdgcn_exp2f(S[jt][r]);
            S[jt][r] = (col <= row) ? p : 0.f;
          }
      } else {
#pragma unroll
        for (int jt = 0; jt < 4; ++jt)
#pragma unroll
          for (int r = 0; r < 4; ++r)
            S[jt][r] = __builtin_amdgcn_exp2f(S[jt][r]);
      }
      // P -> per-wave Pt (transposed [key][qrow]): 4 vector b64 writes
#pragma unroll
      for (int jt = 0; jt < 4; ++jt) {
        ushort4 pw;
        pw.x = f2bf(S[jt][0]); pw.y = f2bf(S[jt][1]);
        pw.z = f2bf(S[jt][2]); pw.w = f2bf(S[jt][3]);
        *(ushort4*)&Pt[w][(jt * 16 + m16) * 16 + g * 4] = pw;
      }
      // A-fragment reload via hardware transpose read (lane stride 8 B in-group)
      s16x4 a0, a1, b0, b1;
      {
        __attribute__((address_space(3))) unsigned short* p3 =
            (__attribute__((address_space(3))) unsigned short*)&Pt[w][g * 128 + m16 * 4];
        unsigned paddr = (unsigned)(size_t)p3;
        asm volatile(
            "s_waitcnt lgkmcnt(0)\n\t"
            "ds_read_b64_tr_b16 %0, %4\n\t"
            "ds_read_b64_tr_b16 %1, %4 offset:128\n\t"
            "ds_read_b64_tr_b16 %2, %4 offset:1024\n\t"
            "ds_read_b64_tr_b16 %3, %4 offset:1152\n\t"
            "s_waitcnt lgkmcnt(0)"
            : "=&v"(a0), "=&v"(a1), "=&v"(b0), "=&v"(b1)
            : "v"(paddr)
            : "memory");
        __builtin_amdgcn_sched_barrier(0);  // rule #18: keep MFMAs below the wait
      }
      bf16x8 pf0 = __builtin_shufflevector(a0, a1, 0, 1, 2, 3, 4, 5, 6, 7);
      bf16x8 pf1 = __builtin_shufflevector(b0, b1, 0, 1, 2, 3, 4, 5, 6, 7);
      // O += P V ; l += P @ 1 (row-sum via matrix pipe)
      __builtin_amdgcn_s_setprio(1);
      lacc = __builtin_amdgcn_mfma_f32_16x16x32_bf16(pf0, ones, lacc, 0, 0, 0);
      lacc = __builtin_amdgcn_mfma_f32_16x16x32_bf16(pf1, ones, lacc, 0, 0, 0);
#pragma unroll
      for (int dt = 0; dt < 4; ++dt) {
        const int rb = (dt * 16 + m16) * 64;
        bf16x8 vf0 = *(const bf16x8*)&VsB[rb + ((g * 8) ^ sw8)];
        bf16x8 vf1 = *(const bf16x8*)&VsB[rb + (((g + 4) * 8) ^ sw8)];
        Oacc[dt] = __builtin_amdgcn_mfma_f32_16x16x32_bf16(pf0, vf0, Oacc[dt], 0, 0, 0);
        Oacc[dt] = __builtin_amdgcn_mfma_f32_16x16x32_bf16(pf1, vf1, Oacc[dt], 0, 0, 0);
      }
      __builtin_amdgcn_s_setprio(0);
    }
    // single barrier per tile: syncs waves AND drains prefetch vmcnt
    __syncthreads();
  }
  // epilogue: lacc[r] already holds the full row sum (MFMA summed over keys)
  float inv[4];
#pragma unroll
  for (int r = 0; r < 4; ++r) inv[r] = 1.0f / lacc[r];
#pragma unroll
  for (int dt = 0; dt < 4; ++dt)
#pragma unroll
    for (int r = 0; r < 4; ++r) {
      int row = qr0 + g * 4 + r;
      qkv[(size_t)(b * LL + row) * QS + h * 64 + dt * 16 + m16] = f2bf(Oacc[dt][r] * inv[r]);
    }
}

// ---------------------------------------------------------------------------
extern "C" void kernel_launch(void* const* d_in, const int* in_sizes, int n_in,
                              void* d_out, int out_size, void* d_ws, size_t ws_size,
                              hipStream_t stream) {
  const void* x = d_in[0];
  const void* cosp = d_in[1];
  const void* sinp = d_in[2];
  const void* Wq = d_in[3];
  const void* Wk = d_in[4];
  const void* Wv = d_in[5];
  const void* Wo = d_in[6];
  float* out = (float*)d_out;

  // ws (bf16): xb [4096][2048] | qkvb [4096][3072] | WqkvT [3072][2048]
  //          | WoT [2048][2048] | Vt [2*8][64][2048]
  char* w0 = (char*)d_ws;
  int* flags = (int*)w0;
  unsigned short* xb = (unsigned short*)(w0 + 256);
  unsigned short* qkvb = xb + (size_t)MM * 2048;
  unsigned short* WqkvT = qkvb + (size_t)MM * QS;
  unsigned short* WoT = WqkvT + (size_t)QS * 2048;
  unsigned short* vt = WoT + (size_t)2048 * 2048;

  detect_all<<<7, 256, 0, stream>>>(
      (const unsigned short*)x, (const unsigned short*)cosp, (const unsigned short*)sinp,
      (const unsigned short*)Wq, (const unsigned short*)Wk, (const unsigned short*)Wv,
      (const unsigned short*)Wo, flags);
  // fused prep: x->bf16 + all 4 weight transposes, one launch
  prep_all<<<10752, 256, 0, stream>>>(x, xb, Wq, Wk, Wv, Wo, WqkvT, WoT, flags);
  // fused QKV projection + RoPE/RMSNorm epilogue (q pre-scaled) + V^T to vt
  gemm_mfma<unsigned short, 1><<<dim3(QS / 128, MM / 128), 256, 0, stream>>>(
      xb, WqkvT, qkvb, MM, QS, 2048, 2048, cosp, sinp, flags, vt);
  // causal GQA attention, QBLK=128, O in-place into q columns; longest first
  attn_mfma<<<dim3(NH, BB, LL / 128), 512, 0, stream>>>(qkvb, vt);
  // output projection: qkv's q columns (lda=3072) @ WoT -> f32 out
  gemm_mfma<float, 0><<<dim3(2048 / 128, MM / 128), 256, 0, stream>>>(
      qkvb, WoT, out, MM, 2048, 2048, QS, nullptr, nullptr, nullptr, nullptr);
}